// Round 2
// baseline (1313.882 us; speedup 1.0000x reference)
//
#include <hip/hip_runtime.h>
#include <cstdint>
#include <cstddef>

// ============================================================================
// transformer_11441792877290 — MI355X fp32 implementation, round 2
// B=4 S=1024 E=1024 H=16 DK=64 FF=2048, SCALE=8, EPS=1e-5
// fp32 inputs/outputs. All GEMMs: 3-term split-bf16 MFMA (hi*hi+hi*lo+lo*hi).
// Raw-reshape quirks handled by scatter epilogues:
//   K:  k.reshape(H,B,DK,S)  -> K2[hb][d2][t], d2=s>>4, t=(s&15)*64+d
//   O:  [H,B,S,DK]->[B,S2,C] -> b2=h>>2, s2=(h&3)*256+b*64+(s>>4), c=(s&15)*64+d
//   FFN (B,S,E)->(B,E,S) raw reshape is a flat no-op (S==E).
// ============================================================================

#define DI __device__ __forceinline__

typedef short s8v __attribute__((ext_vector_type(8)));
typedef float f4v __attribute__((ext_vector_type(4)));
typedef unsigned u4v __attribute__((ext_vector_type(4)));
typedef unsigned u2v __attribute__((ext_vector_type(2)));

DI float bf2f(short u){
  union { unsigned int i; float f; } v;
  v.i = ((unsigned int)(unsigned short)u) << 16;
  return v.f;
}
DI short f2bf(float f){  // round-to-nearest-even
  union { float f; unsigned int i; } v; v.f = f;
  unsigned int x = v.i;
  return (short)((x + 0x7fffu + ((x >> 16) & 1u)) >> 16);
}
DI unsigned pack2(short hi, short lo){
  return ((unsigned)(unsigned short)lo << 16) | (unsigned)(unsigned short)hi;
}

// ---------------------------------------------------------------------------
// fp32 -> bf16 hi/lo plane split
// ---------------------------------------------------------------------------
__launch_bounds__(256)
__global__ void split_k(const float* __restrict__ src, short* __restrict__ hi,
                        short* __restrict__ lo, int n){
  int i = (blockIdx.x * 256 + threadIdx.x) << 2;
  if (i >= n) return;
  float4 v = *(const float4*)(src + i);
  float xs[4] = {v.x, v.y, v.z, v.w};
  short h[4], l[4];
  #pragma unroll
  for (int c = 0; c < 4; c++){
    h[c] = f2bf(xs[c]);
    l[c] = f2bf(xs[c] - bf2f(h[c]));
  }
  *(short4*)(hi + i) = make_short4(h[0], h[1], h[2], h[3]);
  *(short4*)(lo + i) = make_short4(l[0], l[1], l[2], l[3]);
}

// ---------------------------------------------------------------------------
// 3-term split-bf16 GEMM: C[M,N] = (Ah+Al)[M,K] x (Bh+Bl)[K,N] (drop lo*lo)
// Block 256 = 4 waves (2x2 of 64x64), tile 128x128, BK=32. M=4096.
// LDS element = u32 (lo<<16|hi).
// BL: 0 = row-major B[k*ldb+n]; 1 = Wqkv gather [H,E,DK]: B[k=e][n=h*64+d]
// EPI:0 = hi/lo scatter to q/v layout  ((h*4+b)*1024+s)*64+d
//     1 = hi/lo scatter to K2 layout   ((h*4+b)*64+(s>>4))*1024+(s&15)*64+d
//     2 = fp32 outf = acc + xres[m*N+n]
//     3 = hi/lo planes = relu(acc + bias[n])
//     4 = fp32 outf = acc + bias[n]
// ---------------------------------------------------------------------------
struct GemmP {
  const short* Ah; const short* Al; int lda;
  const short* Bh; const short* Bl; int ldb;
  int K; int N;
  const float* xres; const float* bias;
  float* outf; short* ohi; short* olo;
};

template<int BL, int EPI>
__launch_bounds__(256, 2)
__global__ void gemm3_k(GemmP p){
  __shared__ unsigned As[128 * 36];   // [m][k] packed, stride 36 dw (bank shift 4)
  __shared__ unsigned Bs[32 * 130];   // [k][n] packed, stride 130 dw (shift 2)
  const int tid = threadIdx.x;
  const int L = tid & 63, w = tid >> 6;
  const int lr = L & 15, lg = L >> 4;
  const int mo = (w >> 1) * 64, no = (w & 1) * 64;
  const int m0 = blockIdx.y * 128, n0 = blockIdx.x * 128;

  f4v acc[4][4];
  #pragma unroll
  for (int i = 0; i < 4; i++)
    #pragma unroll
    for (int j = 0; j < 4; j++)
      #pragma unroll
      for (int r = 0; r < 4; r++) acc[i][j][r] = 0.0f;

  const int nkt = p.K >> 5;
  for (int kt = 0; kt < nkt; kt++){
    const int k0 = kt << 5;
    // ---- stage A (128x32), 8 elems/thread-chunk, 2 chunks
    #pragma unroll
    for (int i = 0; i < 2; i++){
      int c = tid + (i << 8);            // 0..511
      int row = c >> 2, col8 = (c & 3) << 3;
      const short* ah = p.Ah + (size_t)(m0 + row) * p.lda + k0 + col8;
      const short* al = p.Al + (size_t)(m0 + row) * p.lda + k0 + col8;
      s8v hv = *(const s8v*)ah;
      s8v lv = *(const s8v*)al;
      unsigned pk[8];
      #pragma unroll
      for (int j = 0; j < 8; j++) pk[j] = pack2(hv[j], lv[j]);
      u4v q0 = {pk[0], pk[1], pk[2], pk[3]};
      u4v q1 = {pk[4], pk[5], pk[6], pk[7]};
      *(u4v*)&As[row * 36 + col8]     = q0;
      *(u4v*)&As[row * 36 + col8 + 4] = q1;
    }
    // ---- stage B (32x128), 8 elems/thread-chunk, 2 chunks
    #pragma unroll
    for (int i = 0; i < 2; i++){
      int c = tid + (i << 8);
      int k = c >> 4, n8 = (c & 15) << 3;
      const short *bh, *bl;
      if (BL == 0){
        size_t off = (size_t)(k0 + k) * p.ldb + n0 + n8;
        bh = p.Bh + off; bl = p.Bl + off;
      } else {
        int cg = n0 + n8;
        size_t off = (size_t)(cg >> 6) * 65536 + (size_t)(k0 + k) * 64 + (cg & 63);
        bh = p.Bh + off; bl = p.Bl + off;
      }
      s8v hv = *(const s8v*)bh;
      s8v lv = *(const s8v*)bl;
      unsigned pk[8];
      #pragma unroll
      for (int j = 0; j < 8; j++) pk[j] = pack2(hv[j], lv[j]);
      int base = k * 130 + n8;
      #pragma unroll
      for (int jj = 0; jj < 4; jj++){
        u2v d2 = {pk[2*jj], pk[2*jj+1]};
        *(u2v*)&Bs[base + 2*jj] = d2;
      }
    }
    __syncthreads();

    // ---- compute: one 32-deep k-step
    const int kbd = lg << 3;
    s8v bh[4], bl[4];
    #pragma unroll
    for (int ni = 0; ni < 4; ni++){
      const int n = no + (ni << 4) + lr;
      #pragma unroll
      for (int j = 0; j < 8; j++){
        unsigned u = Bs[(kbd + j) * 130 + n];
        bh[ni][j] = (short)(u & 0xffffu);
        bl[ni][j] = (short)(u >> 16);
      }
    }
    s8v ah[4], al[4];
    #pragma unroll
    for (int mi = 0; mi < 4; mi++){
      const int row = mo + (mi << 4) + lr;
      u4v a0 = *(const u4v*)&As[row * 36 + kbd];
      u4v a1 = *(const u4v*)&As[row * 36 + kbd + 4];
      #pragma unroll
      for (int j = 0; j < 4; j++){
        ah[mi][j]     = (short)(a0[j] & 0xffffu);
        al[mi][j]     = (short)(a0[j] >> 16);
        ah[mi][4 + j] = (short)(a1[j] & 0xffffu);
        al[mi][4 + j] = (short)(a1[j] >> 16);
      }
    }
    #pragma unroll
    for (int mi = 0; mi < 4; mi++)
      #pragma unroll
      for (int ni = 0; ni < 4; ni++){
        acc[mi][ni] = __builtin_amdgcn_mfma_f32_16x16x32_bf16(ah[mi], bh[ni], acc[mi][ni], 0, 0, 0);
        acc[mi][ni] = __builtin_amdgcn_mfma_f32_16x16x32_bf16(ah[mi], bl[ni], acc[mi][ni], 0, 0, 0);
        acc[mi][ni] = __builtin_amdgcn_mfma_f32_16x16x32_bf16(al[mi], bh[ni], acc[mi][ni], 0, 0, 0);
      }
    __syncthreads();
  }

  // ---- epilogue (C/D map: col = lane&15, row = (lane>>4)*4 + reg)
  #pragma unroll
  for (int mi = 0; mi < 4; mi++){
    #pragma unroll
    for (int ni = 0; ni < 4; ni++){
      #pragma unroll
      for (int r = 0; r < 4; r++){
        float val = acc[mi][ni][r];
        int m = m0 + mo + (mi << 4) + (lg << 2) + r;
        int n = n0 + no + (ni << 4) + lr;
        if (EPI == 0 || EPI == 1){
          int b = m >> 10, s = m & 1023, h = n >> 6, d = n & 63;
          size_t dst;
          if (EPI == 0)
            dst = (((size_t)(((h << 2) | b) << 10) + s) << 6) + d;
          else
            dst = (((size_t)(((h << 2) | b) << 6) + (s >> 4)) << 10) + ((s & 15) << 6) + d;
          short hi = f2bf(val);
          p.ohi[dst] = hi;
          p.olo[dst] = f2bf(val - bf2f(hi));
        } else if (EPI == 2){
          size_t o = (size_t)m * p.N + n;
          p.outf[o] = val + p.xres[o];
        } else if (EPI == 3){
          float x = val + p.bias[n];
          x = x > 0.0f ? x : 0.0f;
          size_t o = (size_t)m * p.N + n;
          short hi = f2bf(x);
          p.ohi[o] = hi;
          p.olo[o] = f2bf(x - bf2f(hi));
        } else {
          p.outf[(size_t)m * p.N + n] = val + p.bias[n];
        }
      }
    }
  }
}

// ---------------------------------------------------------------------------
// Flash attention per (h,b): Q[1024,64] x K2[64,1024] -> softmax/8 -> x V
// hi/lo bf16 operand planes; 3-term split MFMAs. Output scattered to the
// raw head-concat reshape layout.
// ---------------------------------------------------------------------------
template<int CAUSAL>
__launch_bounds__(256, 2)
__global__ void flash_k(const short* __restrict__ qhi, const short* __restrict__ qlo,
                        const short* __restrict__ khi, const short* __restrict__ klo,
                        const short* __restrict__ vhi, const short* __restrict__ vlo,
                        short* __restrict__ ohi_g, short* __restrict__ olo_g){
  __shared__ short Kt[2][64*66];   // [d][t]
  __shared__ short Vt[2][64*66];   // [t][d]
  __shared__ short Ph[4][16*72];   // per-wave P strip [16 s][64 t]
  __shared__ short Pl[4][16*72];
  const int tid = threadIdx.x, L = tid & 63, w = tid >> 6;
  const int si = blockIdx.x, hb = blockIdx.y;
  const int h = hb >> 2, b = hb & 3;
  const size_t hbo = (size_t)hb << 16;
  const int s0w = (si << 6) + (w << 4);
  const int lr = L & 15, lg = L >> 4;
  const float NEG_INF = -__builtin_inff();

  s8v qh[2], ql[2];
  {
    const size_t qoff = hbo + (size_t)(s0w + lr) * 64 + (lg << 3);
    qh[0] = *(const s8v*)(qhi + qoff);  qh[1] = *(const s8v*)(qhi + qoff + 32);
    ql[0] = *(const s8v*)(qlo + qoff);  ql[1] = *(const s8v*)(qlo + qoff + 32);
  }

  f4v o[4];
  float mprev[4], lsum[4];
  #pragma unroll
  for (int ni = 0; ni < 4; ni++)
    #pragma unroll
    for (int r = 0; r < 4; r++) o[ni][r] = 0.0f;
  #pragma unroll
  for (int r = 0; r < 4; r++){ mprev[r] = NEG_INF; lsum[r] = 0.0f; }

  const int ntt = CAUSAL ? (si + 1) : 16;
  for (int ti = 0; ti < ntt; ti++){
    const int t0 = ti << 6;
    __syncthreads();
    #pragma unroll
    for (int i = 0; i < 8; i++){
      int c = tid + (i << 8);
      int buf = c >> 9, cc = c & 511, row = cc >> 3, col8 = (cc & 7) << 3;
      const short* g; short* dst;
      if      (buf == 0){ g = khi + hbo + (size_t)row * 1024 + t0 + col8; dst = &Kt[0][row*66 + col8]; }
      else if (buf == 1){ g = klo + hbo + (size_t)row * 1024 + t0 + col8; dst = &Kt[1][row*66 + col8]; }
      else if (buf == 2){ g = vhi + hbo + (size_t)(t0 + row) * 64 + col8; dst = &Vt[0][row*66 + col8]; }
      else              { g = vlo + hbo + (size_t)(t0 + row) * 64 + col8; dst = &Vt[1][row*66 + col8]; }
      union { s8v s; unsigned u[4]; } uv; uv.s = *(const s8v*)g;
      unsigned* d32 = (unsigned*)dst;
      #pragma unroll
      for (int jj = 0; jj < 4; jj++) d32[jj] = uv.u[jj];
    }
    __syncthreads();

    f4v sa[4];
    #pragma unroll
    for (int ni = 0; ni < 4; ni++)
      #pragma unroll
      for (int r = 0; r < 4; r++) sa[ni][r] = 0.0f;
    #pragma unroll
    for (int ks = 0; ks < 2; ks++){
      const int kb = (ks << 5) + (lg << 3);
      s8v kbh[4], kbl[4];
      #pragma unroll
      for (int ni = 0; ni < 4; ni++){
        const int n = (ni << 4) + lr;
        #pragma unroll
        for (int j = 0; j < 8; j++){
          kbh[ni][j] = Kt[0][(kb + j) * 66 + n];
          kbl[ni][j] = Kt[1][(kb + j) * 66 + n];
        }
      }
      #pragma unroll
      for (int ni = 0; ni < 4; ni++){
        sa[ni] = __builtin_amdgcn_mfma_f32_16x16x32_bf16(qh[ks], kbh[ni], sa[ni], 0, 0, 0);
        sa[ni] = __builtin_amdgcn_mfma_f32_16x16x32_bf16(qh[ks], kbl[ni], sa[ni], 0, 0, 0);
        sa[ni] = __builtin_amdgcn_mfma_f32_16x16x32_bf16(ql[ks], kbh[ni], sa[ni], 0, 0, 0);
      }
    }

    float tm[4] = {NEG_INF, NEG_INF, NEG_INF, NEG_INF};
    #pragma unroll
    for (int ni = 0; ni < 4; ni++){
      #pragma unroll
      for (int r = 0; r < 4; r++){
        float v = sa[ni][r] * 0.125f;
        if (CAUSAL){
          int tg = t0 + (ni << 4) + lr;
          int sg = s0w + (lg << 2) + r;
          if (tg > sg) v = NEG_INF;
        }
        sa[ni][r] = v;
        tm[r] = fmaxf(tm[r], v);
      }
    }
    #pragma unroll
    for (int off = 1; off < 16; off <<= 1)
      #pragma unroll
      for (int r = 0; r < 4; r++) tm[r] = fmaxf(tm[r], __shfl_xor(tm[r], off, 16));

    float alpha[4], psum[4];
    #pragma unroll
    for (int r = 0; r < 4; r++){
      float mn = fmaxf(mprev[r], tm[r]);
      alpha[r] = __expf(mprev[r] - mn);
      mprev[r] = mn;
      psum[r] = 0.0f;
    }
    #pragma unroll
    for (int ni = 0; ni < 4; ni++)
      #pragma unroll
      for (int r = 0; r < 4; r++){
        float pv = __expf(sa[ni][r] - mprev[r]);
        sa[ni][r] = pv;
        psum[r] += pv;
      }
    #pragma unroll
    for (int off = 1; off < 16; off <<= 1)
      #pragma unroll
      for (int r = 0; r < 4; r++) psum[r] += __shfl_xor(psum[r], off, 16);
    #pragma unroll
    for (int r = 0; r < 4; r++) lsum[r] = lsum[r] * alpha[r] + psum[r];
    #pragma unroll
    for (int ni = 0; ni < 4; ni++)
      #pragma unroll
      for (int r = 0; r < 4; r++) o[ni][r] *= alpha[r];

    #pragma unroll
    for (int ni = 0; ni < 4; ni++)
      #pragma unroll
      for (int r = 0; r < 4; r++){
        int prow = (lg << 2) + r, pcol = (ni << 4) + lr;
        float pv = sa[ni][r];
        short hi = f2bf(pv);
        Ph[w][prow * 72 + pcol] = hi;
        Pl[w][prow * 72 + pcol] = f2bf(pv - bf2f(hi));
      }
    __syncthreads();
    #pragma unroll
    for (int ks = 0; ks < 2; ks++){
      const int kb = (ks << 5) + (lg << 3);
      s8v ph = *(const s8v*)&Ph[w][lr * 72 + kb];
      s8v pl = *(const s8v*)&Pl[w][lr * 72 + kb];
      s8v vbh[4], vbl[4];
      #pragma unroll
      for (int ni = 0; ni < 4; ni++){
        const int n = (ni << 4) + lr;
        #pragma unroll
        for (int j = 0; j < 8; j++){
          vbh[ni][j] = Vt[0][(kb + j) * 66 + n];
          vbl[ni][j] = Vt[1][(kb + j) * 66 + n];
        }
      }
      #pragma unroll
      for (int ni = 0; ni < 4; ni++){
        o[ni] = __builtin_amdgcn_mfma_f32_16x16x32_bf16(ph, vbh[ni], o[ni], 0, 0, 0);
        o[ni] = __builtin_amdgcn_mfma_f32_16x16x32_bf16(ph, vbl[ni], o[ni], 0, 0, 0);
        o[ni] = __builtin_amdgcn_mfma_f32_16x16x32_bf16(pl, vbh[ni], o[ni], 0, 0, 0);
      }
    }
  }

  #pragma unroll
  for (int ni = 0; ni < 4; ni++){
    #pragma unroll
    for (int r = 0; r < 4; r++){
      float val = o[ni][r] / lsum[r];
      int s = s0w + (lg << 2) + r;
      int d = (ni << 4) + lr;
      int s2i = ((h & 3) << 8) | (b << 6) | (s >> 4);
      int c   = ((s & 15) << 6) | d;
      size_t dst = ((size_t)(h >> 2) << 20) + ((size_t)s2i << 10) + c;
      short hi = f2bf(val);
      ohi_g[dst] = hi;
      olo_g[dst] = f2bf(val - bf2f(hi));
    }
  }
}

// ---------------------------------------------------------------------------
// LayerNorm over (S,E) = 1M elems per batch, three-stage.
// ---------------------------------------------------------------------------
__launch_bounds__(256)
__global__ void ln_partial_k(const float* s1, const float* s2, float2* part){
  const int tid = threadIdx.x, L = tid & 63, w = tid >> 6;
  const int b = blockIdx.y, j = blockIdx.x;
  const size_t base = ((size_t)b << 20) + ((size_t)j << 13) + ((size_t)tid << 2);
  float sum = 0.0f, ss = 0.0f;
  #pragma unroll
  for (int i = 0; i < 8; i++){
    size_t idx = base + ((size_t)i << 10);
    float4 v = *(const float4*)(s1 + idx);
    if (s2){
      float4 u = *(const float4*)(s2 + idx);
      v.x += u.x; v.y += u.y; v.z += u.z; v.w += u.w;
    }
    sum += v.x + v.y + v.z + v.w;
    ss  += v.x*v.x + v.y*v.y + v.z*v.z + v.w*v.w;
  }
  #pragma unroll
  for (int off = 1; off < 64; off <<= 1){
    sum += __shfl_xor(sum, off, 64);
    ss  += __shfl_xor(ss,  off, 64);
  }
  __shared__ float red[4][2];
  if (L == 0){ red[w][0] = sum; red[w][1] = ss; }
  __syncthreads();
  if (tid == 0){
    float s_ = red[0][0] + red[1][0] + red[2][0] + red[3][0];
    float q_ = red[0][1] + red[1][1] + red[2][1] + red[3][1];
    part[b * 128 + j] = make_float2(s_, q_);
  }
}

__launch_bounds__(64)
__global__ void ln_final_k(const float2* part, float2* stats){
  const int b = blockIdx.x, t = threadIdx.x;
  float2 a = part[b * 128 + t], c = part[b * 128 + 64 + t];
  float sum = a.x + c.x, ss = a.y + c.y;
  #pragma unroll
  for (int off = 1; off < 64; off <<= 1){
    sum += __shfl_xor(sum, off, 64);
    ss  += __shfl_xor(ss,  off, 64);
  }
  if (t == 0){
    float mean = sum * (1.0f / 1048576.0f);
    float var  = ss  * (1.0f / 1048576.0f) - mean * mean;
    stats[b] = make_float2(mean, rsqrtf(var + 1e-5f));
  }
}

// MODE 0: hi/lo planes | MODE 1: fp32 + hi/lo planes | MODE 2: fp32 out only
template<int MODE>
__launch_bounds__(256)
__global__ void ln_apply_k(const float* s1, const float* s2,
                           const float* wgt, const float* bias,
                           const float2* stats,
                           float* dstf, short* dsta, short* dstb){
  const int tid = threadIdx.x;
  const size_t base = ((size_t)blockIdx.x << 11) + ((size_t)tid << 2);
  #pragma unroll
  for (int i = 0; i < 2; i++){
    size_t idx = base + ((size_t)i << 10);
    int b = (int)(idx >> 20);
    float2 st = stats[b];
    float4 x = *(const float4*)(s1 + idx);
    if (s2){
      float4 u = *(const float4*)(s2 + idx);
      x.x += u.x; x.y += u.y; x.z += u.z; x.w += u.w;
    }
    unsigned wi = (unsigned)(idx & 1048575u);
    float4 wv = *(const float4*)(wgt + wi);
    float4 bv = *(const float4*)(bias + wi);
    float xv[4] = {x.x, x.y, x.z, x.w};
    float wvv[4] = {wv.x, wv.y, wv.z, wv.w};
    float bvv[4] = {bv.x, bv.y, bv.z, bv.w};
    float yv[4];
    #pragma unroll
    for (int c = 0; c < 4; c++)
      yv[c] = (xv[c] - st.x) * st.y * wvv[c] + bvv[c];
    if (MODE == 0 || MODE == 1){
      short h[4], l[4];
      #pragma unroll
      for (int c = 0; c < 4; c++){
        h[c] = f2bf(yv[c]);
        l[c] = f2bf(yv[c] - bf2f(h[c]));
      }
      *(short4*)(dsta + idx) = make_short4(h[0], h[1], h[2], h[3]);
      *(short4*)(dstb + idx) = make_short4(l[0], l[1], l[2], l[3]);
      if (MODE == 1)
        *(float4*)(dstf + idx) = make_float4(yv[0], yv[1], yv[2], yv[3]);
    } else {
      *(float4*)(dstf + idx) = make_float4(yv[0], yv[1], yv[2], yv[3]);
    }
  }
}

// ---------------------------------------------------------------------------
extern "C" void kernel_launch(void* const* d_in, const int* in_sizes, int n_in,
                              void* d_out, int out_size, void* d_ws, size_t ws_size,
                              hipStream_t stream){
  const float* IRf = (const float*)d_in[0];
  const float* OEf = (const float*)d_in[1];
  const float* Wq1f = (const float*)d_in[2];
  const float* Wk1f = (const float*)d_in[3];
  const float* Wv1f = (const float*)d_in[4];
  const float* Wo1f = (const float*)d_in[5];
  const float* Wq2f = (const float*)d_in[6];
  const float* Wk2f = (const float*)d_in[7];
  const float* Wv2f = (const float*)d_in[8];
  const float* Wo2f = (const float*)d_in[9];
  const float* ln1w = (const float*)d_in[10];
  const float* ln1b = (const float*)d_in[11];
  const float* ln2w = (const float*)d_in[12];
  const float* ln2b = (const float*)d_in[13];
  const float* ln3w = (const float*)d_in[14];
  const float* ln3b = (const float*)d_in[15];
  const float* W1f = (const float*)d_in[16];
  const float* b1f = (const float*)d_in[17];
  const float* W2f = (const float*)d_in[18];
  const float* b2f = (const float*)d_in[19];
  float* dout = (float*)d_out;

  char* ws = (char*)d_ws;
  const size_t MB = (size_t)1 << 20;
  short* OEh = (short*)(ws + 0*MB),  *OEl = (short*)(ws + 8*MB);
  short* IRh = (short*)(ws + 16*MB), *IRl = (short*)(ws + 24*MB);
  short* Wq1h = (short*)(ws + 32*MB), *Wq1l = (short*)(ws + 34*MB);
  short* Wk1h = (short*)(ws + 36*MB), *Wk1l = (short*)(ws + 38*MB);
  short* Wv1h = (short*)(ws + 40*MB), *Wv1l = (short*)(ws + 42*MB);
  short* Wo1h = (short*)(ws + 44*MB), *Wo1l = (short*)(ws + 46*MB);
  short* Wq2h = (short*)(ws + 48*MB), *Wq2l = (short*)(ws + 50*MB);
  short* Wk2h = (short*)(ws + 52*MB), *Wk2l = (short*)(ws + 54*MB);
  short* Wv2h = (short*)(ws + 56*MB), *Wv2l = (short*)(ws + 58*MB);
  short* Wo2h = (short*)(ws + 60*MB), *Wo2l = (short*)(ws + 62*MB);
  short* W1h = (short*)(ws + 64*MB), *W1l = (short*)(ws + 68*MB);
  short* W2h = (short*)(ws + 72*MB), *W2l = (short*)(ws + 76*MB);
  short* q_h = (short*)(ws + 80*MB),  *q_l = (short*)(ws + 88*MB);
  short* k_h = (short*)(ws + 96*MB),  *k_l = (short*)(ws + 104*MB);
  short* v_h = (short*)(ws + 112*MB), *v_l = (short*)(ws + 120*MB);
  short* outr_h = (short*)(ws + 128*MB), *outr_l = (short*)(ws + 136*MB);
  float* resid = (float*)(ws + 144*MB);
  short* attn_h = (short*)(ws + 160*MB), *attn_l = (short*)(ws + 168*MB);
  float* att2n_f = (float*)(ws + 176*MB);
  // aliases (dead ranges)
  short* hid_h = (short*)(ws + 80*MB);   // over q planes (dead after flash2)
  short* hid_l = (short*)(ws + 96*MB);   // over k planes
  float* fc    = (float*)(ws + 112*MB);  // over v planes
  short* a2n_h = (short*)(ws + 160*MB);  // over attn planes (dead after Q2 gemm)
  short* a2n_l = (short*)(ws + 168*MB);
  float2* part  = (float2*)(ws + 192*MB);
  float2* stats = (float2*)(ws + 192*MB + 65536);

  dim3 blk(256);
  dim3 g8(8, 32), g16(16, 32);

  // ---- split all fp32 operands into bf16 hi/lo planes
  split_k<<<dim3(4096), blk, 0, stream>>>(OEf, OEh, OEl, 1 << 22);
  split_k<<<dim3(4096), blk, 0, stream>>>(IRf, IRh, IRl, 1 << 22);
  split_k<<<dim3(1024), blk, 0, stream>>>(Wq1f, Wq1h, Wq1l, 1 << 20);
  split_k<<<dim3(1024), blk, 0, stream>>>(Wk1f, Wk1h, Wk1l, 1 << 20);
  split_k<<<dim3(1024), blk, 0, stream>>>(Wv1f, Wv1h, Wv1l, 1 << 20);
  split_k<<<dim3(1024), blk, 0, stream>>>(Wo1f, Wo1h, Wo1l, 1 << 20);
  split_k<<<dim3(1024), blk, 0, stream>>>(Wq2f, Wq2h, Wq2l, 1 << 20);
  split_k<<<dim3(1024), blk, 0, stream>>>(Wk2f, Wk2h, Wk2l, 1 << 20);
  split_k<<<dim3(1024), blk, 0, stream>>>(Wv2f, Wv2h, Wv2l, 1 << 20);
  split_k<<<dim3(1024), blk, 0, stream>>>(Wo2f, Wo2h, Wo2l, 1 << 20);
  split_k<<<dim3(2048), blk, 0, stream>>>(W1f, W1h, W1l, 1 << 21);
  split_k<<<dim3(2048), blk, 0, stream>>>(W2f, W2h, W2l, 1 << 21);

  GemmP p{};

  // ===== MHA1 (self, causal) =====
  p = {OEh, OEl, 1024, Wq1h, Wq1l, 0, 1024, 1024, nullptr, nullptr, nullptr, q_h, q_l};
  gemm3_k<1,0><<<g8, blk, 0, stream>>>(p);
  p = {OEh, OEl, 1024, Wk1h, Wk1l, 0, 1024, 1024, nullptr, nullptr, nullptr, k_h, k_l};
  gemm3_k<1,1><<<g8, blk, 0, stream>>>(p);
  p = {OEh, OEl, 1024, Wv1h, Wv1l, 0, 1024, 1024, nullptr, nullptr, nullptr, v_h, v_l};
  gemm3_k<1,0><<<g8, blk, 0, stream>>>(p);
  flash_k<1><<<dim3(16, 64), blk, 0, stream>>>(q_h, q_l, k_h, k_l, v_h, v_l, outr_h, outr_l);
  p = {outr_h, outr_l, 1024, Wo1h, Wo1l, 1024, 1024, 1024, OEf, nullptr, resid, nullptr, nullptr};
  gemm3_k<0,2><<<g8, blk, 0, stream>>>(p);
  ln_partial_k<<<dim3(128, 4), blk, 0, stream>>>(resid, nullptr, part);
  ln_final_k<<<dim3(4), dim3(64), 0, stream>>>(part, stats);
  ln_apply_k<0><<<dim3(2048), blk, 0, stream>>>(resid, nullptr, ln1w, ln1b, stats, nullptr, attn_h, attn_l);

  // ===== MHA2 (cross: KV from inputRes, Q from att_norm, no mask) =====
  p = {attn_h, attn_l, 1024, Wq2h, Wq2l, 0, 1024, 1024, nullptr, nullptr, nullptr, q_h, q_l};
  gemm3_k<1,0><<<g8, blk, 0, stream>>>(p);
  p = {IRh, IRl, 1024, Wk2h, Wk2l, 0, 1024, 1024, nullptr, nullptr, nullptr, k_h, k_l};
  gemm3_k<1,1><<<g8, blk, 0, stream>>>(p);
  p = {IRh, IRl, 1024, Wv2h, Wv2l, 0, 1024, 1024, nullptr, nullptr, nullptr, v_h, v_l};
  gemm3_k<1,0><<<g8, blk, 0, stream>>>(p);
  flash_k<0><<<dim3(16, 64), blk, 0, stream>>>(q_h, q_l, k_h, k_l, v_h, v_l, outr_h, outr_l);
  p = {outr_h, outr_l, 1024, Wo2h, Wo2l, 1024, 1024, 1024, OEf, nullptr, resid, nullptr, nullptr};
  gemm3_k<0,2><<<g8, blk, 0, stream>>>(p);
  ln_partial_k<<<dim3(128, 4), blk, 0, stream>>>(resid, nullptr, part);
  ln_final_k<<<dim3(4), dim3(64), 0, stream>>>(part, stats);
  ln_apply_k<1><<<dim3(2048), blk, 0, stream>>>(resid, nullptr, ln2w, ln2b, stats, att2n_f, a2n_h, a2n_l);

  // ===== FFN ((B,S,E)->(B,E,S) raw reshape is a flat no-op) =====
  p = {a2n_h, a2n_l, 1024, W1h, W1l, 2048, 1024, 2048, nullptr, b1f, nullptr, hid_h, hid_l};
  gemm3_k<0,3><<<g16, blk, 0, stream>>>(p);
  p = {hid_h, hid_l, 2048, W2h, W2l, 1024, 2048, 1024, nullptr, b2f, fc, nullptr, nullptr};
  gemm3_k<0,4><<<g8, blk, 0, stream>>>(p);
  ln_partial_k<<<dim3(128, 4), blk, 0, stream>>>(fc, att2n_f, part);
  ln_final_k<<<dim3(4), dim3(64), 0, stream>>>(part, stats);
  ln_apply_k<2><<<dim3(2048), blk, 0, stream>>>(fc, att2n_f, ln3w, ln3b, stats, dout, nullptr, nullptr);
}

// Round 3
// 1162.093 us; speedup vs baseline: 1.1306x; 1.1306x over previous
//
#include <hip/hip_runtime.h>
#include <cstdint>
#include <cstddef>

// ============================================================================
// transformer_11441792877290 — MI355X fp32, round 3
// B=4 S=1024 E=1024 H=16 DK=64 FF=2048, SCALE=8, EPS=1e-5
// Changes vs round 2 (passed, 1314us, absmax 0.10):
//  * K stored as K2^T[hb][t][dd], V as V^T[hb][d][s]  -> flash B-frags are
//    ds_read_b128 rows (was 64 scalar ds_read_u16 per wave per tile)
//  * flash P packed u32 per-wave (no barrier before PV; 3 -> 2 barriers/tile)
//  * GEMM A staged as two separate bf16 planes (b128 in/out, zero pack/unpack
//    VALU on A side); B stays packed [k][n] u32 (proven layout)
//  * FFN GEMMs 2-term split (post-softmax linear path); rest 3-term
//  * 12 split kernels merged into one dispatch
// ============================================================================

#define DI __device__ __forceinline__

typedef short s8v __attribute__((ext_vector_type(8)));
typedef float f4v __attribute__((ext_vector_type(4)));
typedef unsigned u4v __attribute__((ext_vector_type(4)));
typedef unsigned u2v __attribute__((ext_vector_type(2)));

DI float bf2f(short u){
  union { unsigned int i; float f; } v;
  v.i = ((unsigned int)(unsigned short)u) << 16;
  return v.f;
}
DI short f2bf(float f){  // round-to-nearest-even
  union { float f; unsigned int i; } v; v.f = f;
  unsigned int x = v.i;
  return (short)((x + 0x7fffu + ((x >> 16) & 1u)) >> 16);
}
DI unsigned pack2(short hi, short lo){
  return ((unsigned)(unsigned short)lo << 16) | (unsigned)(unsigned short)hi;
}

// ---------------------------------------------------------------------------
// fp32 -> bf16 hi/lo plane split, all 12 tensors in one dispatch
// ---------------------------------------------------------------------------
struct SplitP {
  const float* src[12];
  short* hi[12];
  short* lo[12];
  int n[12];
};

__launch_bounds__(256)
__global__ void splitall_k(SplitP sp){
  const int t = blockIdx.y;
  int i = (blockIdx.x * 256 + threadIdx.x) << 2;
  if (i >= sp.n[t]) return;
  float4 v = *(const float4*)(sp.src[t] + i);
  float xs[4] = {v.x, v.y, v.z, v.w};
  short h[4], l[4];
  #pragma unroll
  for (int c = 0; c < 4; c++){
    h[c] = f2bf(xs[c]);
    l[c] = f2bf(xs[c] - bf2f(h[c]));
  }
  *(short4*)(sp.hi[t] + i) = make_short4(h[0], h[1], h[2], h[3]);
  *(short4*)(sp.lo[t] + i) = make_short4(l[0], l[1], l[2], l[3]);
}

// ---------------------------------------------------------------------------
// Split-bf16 GEMM: C[M,N] = (Ah+Al)[M,K] x (Bh+Bl)[K,N]
// TERMS=3: hi*hi + hi*lo + lo*hi ; TERMS=2: hi*hi + hi*lo
// Block 256 = 4 waves (2x2 of 64x64), tile 128x128, BK=32. M=4096.
// A in LDS: two short planes [m][k] stride 40 (b128 in/out, no pack).
// B in LDS: packed u32 [k][n] stride 130 (proven round-2 layout).
// BL: 0 = row-major B[k*ldb+n]; 1 = Wqkv gather [H,E,DK]: B[k=e][n=h*64+d]
// EPI:0 = hi/lo scatter, q layout   (hb<<16)+(s<<6)+d
//     1 = hi/lo scatter, K2^T       (hb<<16)+(t<<6)+dd   t=(s&15)*64+d, dd=s>>4
//     5 = hi/lo scatter, V^T        (hb<<16)+(d<<10)+s
//     2 = fp32 outf = acc + xres[m*N+n]
//     3 = hi/lo planes = relu(acc + bias[n])
//     4 = fp32 outf = acc + bias[n]
// ---------------------------------------------------------------------------
struct GemmP {
  const short* Ah; const short* Al; int lda;
  const short* Bh; const short* Bl; int ldb;
  int K; int N;
  const float* xres; const float* bias;
  float* outf; short* ohi; short* olo;
};

template<int BL, int EPI, int TERMS>
__launch_bounds__(256, 3)
__global__ void gemm3_k(GemmP p){
  __shared__ short Ash[128 * 40];
  __shared__ short Asl[128 * 40];
  __shared__ unsigned Bs[32 * 130];
  const int tid = threadIdx.x;
  const int L = tid & 63, w = tid >> 6;
  const int lr = L & 15, lg = L >> 4;
  const int mo = (w >> 1) * 64, no = (w & 1) * 64;
  const int m0 = blockIdx.y * 128, n0 = blockIdx.x * 128;

  f4v acc[4][4];
  #pragma unroll
  for (int i = 0; i < 4; i++)
    #pragma unroll
    for (int j = 0; j < 4; j++)
      #pragma unroll
      for (int r = 0; r < 4; r++) acc[i][j][r] = 0.0f;

  const int nkt = p.K >> 5;
  for (int kt = 0; kt < nkt; kt++){
    const int k0 = kt << 5;
    // ---- stage A (128x32, two planes), b128 in / b128 out
    #pragma unroll
    for (int i = 0; i < 2; i++){
      int c = tid + (i << 8);            // 0..511
      int row = c >> 2, col8 = (c & 3) << 3;
      size_t off = (size_t)(m0 + row) * p.lda + k0 + col8;
      *(s8v*)&Ash[row * 40 + col8] = *(const s8v*)(p.Ah + off);
      *(s8v*)&Asl[row * 40 + col8] = *(const s8v*)(p.Al + off);
    }
    // ---- stage B (32x128) packed u32 [k][n] stride 130
    #pragma unroll
    for (int i = 0; i < 2; i++){
      int c = tid + (i << 8);
      int k = c >> 4, n8 = (c & 15) << 3;
      const short *bh, *bl;
      if (BL == 0){
        size_t off = (size_t)(k0 + k) * p.ldb + n0 + n8;
        bh = p.Bh + off; bl = p.Bl + off;
      } else {
        int cg = n0 + n8;
        size_t off = (size_t)(cg >> 6) * 65536 + (size_t)(k0 + k) * 64 + (cg & 63);
        bh = p.Bh + off; bl = p.Bl + off;
      }
      s8v hv = *(const s8v*)bh;
      s8v lv = *(const s8v*)bl;
      unsigned pk[8];
      #pragma unroll
      for (int j = 0; j < 8; j++) pk[j] = pack2(hv[j], lv[j]);
      int base = k * 130 + n8;
      #pragma unroll
      for (int jj = 0; jj < 4; jj++){
        u2v d2 = {pk[2*jj], pk[2*jj+1]};
        *(u2v*)&Bs[base + 2*jj] = d2;
      }
    }
    __syncthreads();

    // ---- compute: one 32-deep k-step
    const int kbd = lg << 3;
    s8v a_h[4], a_l[4];
    #pragma unroll
    for (int mi = 0; mi < 4; mi++){
      const int row = mo + (mi << 4) + lr;
      a_h[mi] = *(const s8v*)&Ash[row * 40 + kbd];
      a_l[mi] = *(const s8v*)&Asl[row * 40 + kbd];
    }
    #pragma unroll
    for (int ni = 0; ni < 4; ni++){
      const int n = no + (ni << 4) + lr;
      s8v bh, bl;
      #pragma unroll
      for (int j = 0; j < 8; j++){
        unsigned u = Bs[(kbd + j) * 130 + n];
        bh[j] = (short)(u & 0xffffu);
        bl[j] = (short)(u >> 16);
      }
      #pragma unroll
      for (int mi = 0; mi < 4; mi++){
        acc[mi][ni] = __builtin_amdgcn_mfma_f32_16x16x32_bf16(a_h[mi], bh, acc[mi][ni], 0, 0, 0);
        acc[mi][ni] = __builtin_amdgcn_mfma_f32_16x16x32_bf16(a_h[mi], bl, acc[mi][ni], 0, 0, 0);
        if (TERMS == 3)
          acc[mi][ni] = __builtin_amdgcn_mfma_f32_16x16x32_bf16(a_l[mi], bh, acc[mi][ni], 0, 0, 0);
      }
    }
    __syncthreads();
  }

  // ---- epilogue (C/D map: col = lane&15, row = (lane>>4)*4 + reg)
  #pragma unroll
  for (int mi = 0; mi < 4; mi++){
    #pragma unroll
    for (int ni = 0; ni < 4; ni++){
      #pragma unroll
      for (int r = 0; r < 4; r++){
        float val = acc[mi][ni][r];
        int m = m0 + mo + (mi << 4) + (lg << 2) + r;
        int n = n0 + no + (ni << 4) + lr;
        if (EPI == 0 || EPI == 1 || EPI == 5){
          int b = m >> 10, s = m & 1023, h = n >> 6, d = n & 63;
          size_t hb16 = (size_t)((h << 2) | b) << 16;
          size_t dst;
          if (EPI == 0)
            dst = hb16 + ((size_t)s << 6) + d;
          else if (EPI == 1)
            dst = hb16 + ((size_t)(((s & 15) << 6) | d) << 6) + (s >> 4);
          else
            dst = hb16 + ((size_t)d << 10) + s;
          short hi = f2bf(val);
          p.ohi[dst] = hi;
          p.olo[dst] = f2bf(val - bf2f(hi));
        } else if (EPI == 2){
          size_t o = (size_t)m * p.N + n;
          p.outf[o] = val + p.xres[o];
        } else if (EPI == 3){
          float x = val + p.bias[n];
          x = x > 0.0f ? x : 0.0f;
          size_t o = (size_t)m * p.N + n;
          short hi = f2bf(x);
          p.ohi[o] = hi;
          p.olo[o] = f2bf(x - bf2f(hi));
        } else {
          p.outf[(size_t)m * p.N + n] = val + p.bias[n];
        }
      }
    }
  }
}

// ---------------------------------------------------------------------------
// Flash attention per (h,b): Q[1024,64] x K2[64,1024] -> softmax/8 -> x V
// K given as K2^T[hb][t][dd]; V as V^T[hb][d][s]. All B-frags ds_read_b128.
// P round-trips per-wave LDS as packed u32 (no barrier needed).
// ---------------------------------------------------------------------------
template<int CAUSAL>
__launch_bounds__(256, 3)
__global__ void flash_k(const short* __restrict__ qhi, const short* __restrict__ qlo,
                        const short* __restrict__ khi, const short* __restrict__ klo,
                        const short* __restrict__ vhi, const short* __restrict__ vlo,
                        short* __restrict__ ohi_g, short* __restrict__ olo_g){
  __shared__ short Kt[2][64*72];     // [t_local][dd]
  __shared__ short Vt[2][64*72];     // [d][t_local]
  __shared__ unsigned Ps[4][16*68];  // per-wave packed P [s_local][t_local]
  const int tid = threadIdx.x, L = tid & 63, w = tid >> 6;
  const int si = blockIdx.x, hb = blockIdx.y;
  const int h = hb >> 2, b = hb & 3;
  const size_t hbo = (size_t)hb << 16;
  const int s0w = (si << 6) + (w << 4);
  const int lr = L & 15, lg = L >> 4;
  const float NEG_INF = -__builtin_inff();

  // Q fragments (A-operand: row = lane&15, k = (lane>>4)*8 + 32*ks)
  s8v qh[2], ql[2];
  {
    const size_t qoff = hbo + (size_t)(s0w + lr) * 64 + (lg << 3);
    qh[0] = *(const s8v*)(qhi + qoff);  qh[1] = *(const s8v*)(qhi + qoff + 32);
    ql[0] = *(const s8v*)(qlo + qoff);  ql[1] = *(const s8v*)(qlo + qoff + 32);
  }

  f4v o[4];
  float mprev[4], lsum[4];
  #pragma unroll
  for (int ni = 0; ni < 4; ni++)
    #pragma unroll
    for (int r = 0; r < 4; r++) o[ni][r] = 0.0f;
  #pragma unroll
  for (int r = 0; r < 4; r++){ mprev[r] = NEG_INF; lsum[r] = 0.0f; }

  const int ntt = CAUSAL ? (si + 1) : 16;
  for (int ti = 0; ti < ntt; ti++){
    const int t0 = ti << 6;
    __syncthreads();
    // ---- stage K2^T tile rows [t][dd] (contiguous 4KB span) and V^T rows [d][t]
    #pragma unroll
    for (int i = 0; i < 8; i++){
      int c = tid + (i << 8);               // 0..2047
      int buf = c >> 9, cc = c & 511, row = cc >> 3, col8 = (cc & 7) << 3;
      const short* g; short* dst;
      if      (buf == 0){ g = khi + hbo + ((size_t)t0 << 6) + (cc << 3);          dst = &Kt[0][cc << 3]; }
      else if (buf == 1){ g = klo + hbo + ((size_t)t0 << 6) + (cc << 3);          dst = &Kt[1][cc << 3]; }
      else if (buf == 2){ g = vhi + hbo + ((size_t)row << 10) + t0 + col8;        dst = &Vt[0][row*72 + col8]; }
      else              { g = vlo + hbo + ((size_t)row << 10) + t0 + col8;        dst = &Vt[1][row*72 + col8]; }
      if (buf < 2) dst = (buf == 0 ? &Kt[0][0] : &Kt[1][0]) + row*72 + col8;
      *(s8v*)dst = *(const s8v*)g;
    }
    __syncthreads();

    // ---- S = Q * K2 (3-term split); B-frag = Kt row t_local, b128
    f4v sa[4];
    #pragma unroll
    for (int ni = 0; ni < 4; ni++)
      #pragma unroll
      for (int r = 0; r < 4; r++) sa[ni][r] = 0.0f;
    #pragma unroll
    for (int ks = 0; ks < 2; ks++){
      const int kb = (ks << 5) + (lg << 3);
      #pragma unroll
      for (int ni = 0; ni < 4; ni++){
        const int tl = (ni << 4) + lr;
        s8v kbh = *(const s8v*)&Kt[0][tl * 72 + kb];
        s8v kbl = *(const s8v*)&Kt[1][tl * 72 + kb];
        sa[ni] = __builtin_amdgcn_mfma_f32_16x16x32_bf16(qh[ks], kbh, sa[ni], 0, 0, 0);
        sa[ni] = __builtin_amdgcn_mfma_f32_16x16x32_bf16(qh[ks], kbl, sa[ni], 0, 0, 0);
        sa[ni] = __builtin_amdgcn_mfma_f32_16x16x32_bf16(ql[ks], kbh, sa[ni], 0, 0, 0);
      }
    }

    // ---- scale (1/8), causal mask, online softmax
    float tm[4] = {NEG_INF, NEG_INF, NEG_INF, NEG_INF};
    #pragma unroll
    for (int ni = 0; ni < 4; ni++){
      #pragma unroll
      for (int r = 0; r < 4; r++){
        float v = sa[ni][r] * 0.125f;
        if (CAUSAL){
          int tg = t0 + (ni << 4) + lr;
          int sg = s0w + (lg << 2) + r;
          if (tg > sg) v = NEG_INF;
        }
        sa[ni][r] = v;
        tm[r] = fmaxf(tm[r], v);
      }
    }
    #pragma unroll
    for (int off = 1; off < 16; off <<= 1)
      #pragma unroll
      for (int r = 0; r < 4; r++) tm[r] = fmaxf(tm[r], __shfl_xor(tm[r], off, 16));

    float alpha[4], psum[4];
    #pragma unroll
    for (int r = 0; r < 4; r++){
      float mn = fmaxf(mprev[r], tm[r]);
      alpha[r] = __expf(mprev[r] - mn);
      mprev[r] = mn;
      psum[r] = 0.0f;
    }
    #pragma unroll
    for (int ni = 0; ni < 4; ni++)
      #pragma unroll
      for (int r = 0; r < 4; r++){
        float pv = __expf(sa[ni][r] - mprev[r]);
        sa[ni][r] = pv;
        psum[r] += pv;
      }
    #pragma unroll
    for (int off = 1; off < 16; off <<= 1)
      #pragma unroll
      for (int r = 0; r < 4; r++) psum[r] += __shfl_xor(psum[r], off, 16);
    #pragma unroll
    for (int r = 0; r < 4; r++) lsum[r] = lsum[r] * alpha[r] + psum[r];
    #pragma unroll
    for (int ni = 0; ni < 4; ni++)
      #pragma unroll
      for (int r = 0; r < 4; r++) o[ni][r] *= alpha[r];

    // ---- P -> per-wave LDS (packed u32), no barrier (same-wave RAW via lgkmcnt)
    #pragma unroll
    for (int ni = 0; ni < 4; ni++)
      #pragma unroll
      for (int r = 0; r < 4; r++){
        int prow = (lg << 2) + r, pcol = (ni << 4) + lr;
        float pv = sa[ni][r];
        short hi = f2bf(pv);
        Ps[w][prow * 68 + pcol] = pack2(hi, f2bf(pv - bf2f(hi)));
      }
    // ---- PV (3-term split); A-frag from Ps (2x b128 + unpack), B-frag = Vt row d
    #pragma unroll
    for (int ks = 0; ks < 2; ks++){
      const int kb = (ks << 5) + (lg << 3);
      u4v p0 = *(const u4v*)&Ps[w][lr * 68 + kb];
      u4v p1 = *(const u4v*)&Ps[w][lr * 68 + kb + 4];
      s8v ph, pl;
      #pragma unroll
      for (int j = 0; j < 4; j++){
        ph[j]   = (short)(p0[j] & 0xffffu);  pl[j]   = (short)(p0[j] >> 16);
        ph[4+j] = (short)(p1[j] & 0xffffu);  pl[4+j] = (short)(p1[j] >> 16);
      }
      #pragma unroll
      for (int ni = 0; ni < 4; ni++){
        const int d = (ni << 4) + lr;
        s8v vbh = *(const s8v*)&Vt[0][d * 72 + kb];
        s8v vbl = *(const s8v*)&Vt[1][d * 72 + kb];
        o[ni] = __builtin_amdgcn_mfma_f32_16x16x32_bf16(ph, vbh, o[ni], 0, 0, 0);
        o[ni] = __builtin_amdgcn_mfma_f32_16x16x32_bf16(ph, vbl, o[ni], 0, 0, 0);
        o[ni] = __builtin_amdgcn_mfma_f32_16x16x32_bf16(pl, vbh, o[ni], 0, 0, 0);
      }
    }
  }

  // ---- normalize, scatter to raw head-concat reshape layout
  #pragma unroll
  for (int ni = 0; ni < 4; ni++){
    #pragma unroll
    for (int r = 0; r < 4; r++){
      float val = o[ni][r] / lsum[r];
      int s = s0w + (lg << 2) + r;
      int d = (ni << 4) + lr;
      int s2i = ((h & 3) << 8) | (b << 6) | (s >> 4);
      int c   = ((s & 15) << 6) | d;
      size_t dst = ((size_t)(h >> 2) << 20) + ((size_t)s2i << 10) + c;
      short hi = f2bf(val);
      ohi_g[dst] = hi;
      olo_g[dst] = f2bf(val - bf2f(hi));
    }
  }
}

// ---------------------------------------------------------------------------
// LayerNorm over (S,E) = 1M elems per batch, three-stage.
// ---------------------------------------------------------------------------
__launch_bounds__(256)
__global__ void ln_partial_k(const float* s1, const float* s2, float2* part){
  const int tid = threadIdx.x, L = tid & 63, w = tid >> 6;
  const int b = blockIdx.y, j = blockIdx.x;
  const size_t base = ((size_t)b << 20) + ((size_t)j << 13) + ((size_t)tid << 2);
  float sum = 0.0f, ss = 0.0f;
  #pragma unroll
  for (int i = 0; i < 8; i++){
    size_t idx = base + ((size_t)i << 10);
    float4 v = *(const float4*)(s1 + idx);
    if (s2){
      float4 u = *(const float4*)(s2 + idx);
      v.x += u.x; v.y += u.y; v.z += u.z; v.w += u.w;
    }
    sum += v.x + v.y + v.z + v.w;
    ss  += v.x*v.x + v.y*v.y + v.z*v.z + v.w*v.w;
  }
  #pragma unroll
  for (int off = 1; off < 64; off <<= 1){
    sum += __shfl_xor(sum, off, 64);
    ss  += __shfl_xor(ss,  off, 64);
  }
  __shared__ float red[4][2];
  if (L == 0){ red[w][0] = sum; red[w][1] = ss; }
  __syncthreads();
  if (tid == 0){
    float s_ = red[0][0] + red[1][0] + red[2][0] + red[3][0];
    float q_ = red[0][1] + red[1][1] + red[2][1] + red[3][1];
    part[b * 128 + j] = make_float2(s_, q_);
  }
}

__launch_bounds__(64)
__global__ void ln_final_k(const float2* part, float2* stats){
  const int b = blockIdx.x, t = threadIdx.x;
  float2 a = part[b * 128 + t], c = part[b * 128 + 64 + t];
  float sum = a.x + c.x, ss = a.y + c.y;
  #pragma unroll
  for (int off = 1; off < 64; off <<= 1){
    sum += __shfl_xor(sum, off, 64);
    ss  += __shfl_xor(ss,  off, 64);
  }
  if (t == 0){
    float mean = sum * (1.0f / 1048576.0f);
    float var  = ss  * (1.0f / 1048576.0f) - mean * mean;
    stats[b] = make_float2(mean, rsqrtf(var + 1e-5f));
  }
}

// MODE 0: hi/lo planes | MODE 1: fp32 + hi/lo planes | MODE 2: fp32 out only
template<int MODE>
__launch_bounds__(256)
__global__ void ln_apply_k(const float* s1, const float* s2,
                           const float* wgt, const float* bias,
                           const float2* stats,
                           float* dstf, short* dsta, short* dstb){
  const int tid = threadIdx.x;
  const size_t base = ((size_t)blockIdx.x << 11) + ((size_t)tid << 2);
  #pragma unroll
  for (int i = 0; i < 2; i++){
    size_t idx = base + ((size_t)i << 10);
    int b = (int)(idx >> 20);
    float2 st = stats[b];
    float4 x = *(const float4*)(s1 + idx);
    if (s2){
      float4 u = *(const float4*)(s2 + idx);
      x.x += u.x; x.y += u.y; x.z += u.z; x.w += u.w;
    }
    unsigned wi = (unsigned)(idx & 1048575u);
    float4 wv = *(const float4*)(wgt + wi);
    float4 bv = *(const float4*)(bias + wi);
    float xv[4] = {x.x, x.y, x.z, x.w};
    float wvv[4] = {wv.x, wv.y, wv.z, wv.w};
    float bvv[4] = {bv.x, bv.y, bv.z, bv.w};
    float yv[4];
    #pragma unroll
    for (int c = 0; c < 4; c++)
      yv[c] = (xv[c] - st.x) * st.y * wvv[c] + bvv[c];
    if (MODE == 0 || MODE == 1){
      short h[4], l[4];
      #pragma unroll
      for (int c = 0; c < 4; c++){
        h[c] = f2bf(yv[c]);
        l[c] = f2bf(yv[c] - bf2f(h[c]));
      }
      *(short4*)(dsta + idx) = make_short4(h[0], h[1], h[2], h[3]);
      *(short4*)(dstb + idx) = make_short4(l[0], l[1], l[2], l[3]);
      if (MODE == 1)
        *(float4*)(dstf + idx) = make_float4(yv[0], yv[1], yv[2], yv[3]);
    } else {
      *(float4*)(dstf + idx) = make_float4(yv[0], yv[1], yv[2], yv[3]);
    }
  }
}

// ---------------------------------------------------------------------------
extern "C" void kernel_launch(void* const* d_in, const int* in_sizes, int n_in,
                              void* d_out, int out_size, void* d_ws, size_t ws_size,
                              hipStream_t stream){
  const float* IRf = (const float*)d_in[0];
  const float* OEf = (const float*)d_in[1];
  const float* Wq1f = (const float*)d_in[2];
  const float* Wk1f = (const float*)d_in[3];
  const float* Wv1f = (const float*)d_in[4];
  const float* Wo1f = (const float*)d_in[5];
  const float* Wq2f = (const float*)d_in[6];
  const float* Wk2f = (const float*)d_in[7];
  const float* Wv2f = (const float*)d_in[8];
  const float* Wo2f = (const float*)d_in[9];
  const float* ln1w = (const float*)d_in[10];
  const float* ln1b = (const float*)d_in[11];
  const float* ln2w = (const float*)d_in[12];
  const float* ln2b = (const float*)d_in[13];
  const float* ln3w = (const float*)d_in[14];
  const float* ln3b = (const float*)d_in[15];
  const float* W1f = (const float*)d_in[16];
  const float* b1f = (const float*)d_in[17];
  const float* W2f = (const float*)d_in[18];
  const float* b2f = (const float*)d_in[19];
  float* dout = (float*)d_out;

  char* ws = (char*)d_ws;
  const size_t MB = (size_t)1 << 20;
  short* OEh = (short*)(ws + 0*MB),  *OEl = (short*)(ws + 8*MB);
  short* IRh = (short*)(ws + 16*MB), *IRl = (short*)(ws + 24*MB);
  short* Wq1h = (short*)(ws + 32*MB), *Wq1l = (short*)(ws + 34*MB);
  short* Wk1h = (short*)(ws + 36*MB), *Wk1l = (short*)(ws + 38*MB);
  short* Wv1h = (short*)(ws + 40*MB), *Wv1l = (short*)(ws + 42*MB);
  short* Wo1h = (short*)(ws + 44*MB), *Wo1l = (short*)(ws + 46*MB);
  short* Wq2h = (short*)(ws + 48*MB), *Wq2l = (short*)(ws + 50*MB);
  short* Wk2h = (short*)(ws + 52*MB), *Wk2l = (short*)(ws + 54*MB);
  short* Wv2h = (short*)(ws + 56*MB), *Wv2l = (short*)(ws + 58*MB);
  short* Wo2h = (short*)(ws + 60*MB), *Wo2l = (short*)(ws + 62*MB);
  short* W1h = (short*)(ws + 64*MB), *W1l = (short*)(ws + 68*MB);
  short* W2h = (short*)(ws + 72*MB), *W2l = (short*)(ws + 76*MB);
  short* q_h = (short*)(ws + 80*MB),  *q_l = (short*)(ws + 88*MB);
  short* k_h = (short*)(ws + 96*MB),  *k_l = (short*)(ws + 104*MB);
  short* v_h = (short*)(ws + 112*MB), *v_l = (short*)(ws + 120*MB);
  short* outr_h = (short*)(ws + 128*MB), *outr_l = (short*)(ws + 136*MB);
  float* resid = (float*)(ws + 144*MB);
  short* attn_h = (short*)(ws + 160*MB), *attn_l = (short*)(ws + 168*MB);
  float* att2n_f = (float*)(ws + 176*MB);
  // aliases (dead ranges)
  short* hid_h = (short*)(ws + 80*MB);   // over q planes (dead after flash2)
  short* hid_l = (short*)(ws + 96*MB);   // over k planes
  float* fc    = (float*)(ws + 112*MB);  // over v planes
  short* a2n_h = (short*)(ws + 160*MB);  // over attn planes (dead after Q2 gemm)
  short* a2n_l = (short*)(ws + 168*MB);
  float2* part  = (float2*)(ws + 192*MB);
  float2* stats = (float2*)(ws + 192*MB + 65536);

  dim3 blk(256);
  dim3 g8(8, 32), g16(16, 32);

  // ---- split all fp32 operands into bf16 hi/lo planes (one dispatch)
  SplitP sp;
  const float* srcs[12] = {OEf, IRf, Wq1f, Wk1f, Wv1f, Wo1f, Wq2f, Wk2f, Wv2f, Wo2f, W1f, W2f};
  short* his[12] = {OEh, IRh, Wq1h, Wk1h, Wv1h, Wo1h, Wq2h, Wk2h, Wv2h, Wo2h, W1h, W2h};
  short* los[12] = {OEl, IRl, Wq1l, Wk1l, Wv1l, Wo1l, Wq2l, Wk2l, Wv2l, Wo2l, W1l, W2l};
  int ns[12] = {1<<22, 1<<22, 1<<20, 1<<20, 1<<20, 1<<20, 1<<20, 1<<20, 1<<20, 1<<20, 1<<21, 1<<21};
  for (int i = 0; i < 12; i++){ sp.src[i] = srcs[i]; sp.hi[i] = his[i]; sp.lo[i] = los[i]; sp.n[i] = ns[i]; }
  splitall_k<<<dim3(4096, 12), blk, 0, stream>>>(sp);

  GemmP p{};

  // ===== MHA1 (self, causal) =====
  p = {OEh, OEl, 1024, Wq1h, Wq1l, 0, 1024, 1024, nullptr, nullptr, nullptr, q_h, q_l};
  gemm3_k<1,0,3><<<g8, blk, 0, stream>>>(p);
  p = {OEh, OEl, 1024, Wk1h, Wk1l, 0, 1024, 1024, nullptr, nullptr, nullptr, k_h, k_l};
  gemm3_k<1,1,3><<<g8, blk, 0, stream>>>(p);
  p = {OEh, OEl, 1024, Wv1h, Wv1l, 0, 1024, 1024, nullptr, nullptr, nullptr, v_h, v_l};
  gemm3_k<1,5,3><<<g8, blk, 0, stream>>>(p);
  flash_k<1><<<dim3(16, 64), blk, 0, stream>>>(q_h, q_l, k_h, k_l, v_h, v_l, outr_h, outr_l);
  p = {outr_h, outr_l, 1024, Wo1h, Wo1l, 1024, 1024, 1024, OEf, nullptr, resid, nullptr, nullptr};
  gemm3_k<0,2,3><<<g8, blk, 0, stream>>>(p);
  ln_partial_k<<<dim3(128, 4), blk, 0, stream>>>(resid, nullptr, part);
  ln_final_k<<<dim3(4), dim3(64), 0, stream>>>(part, stats);
  ln_apply_k<0><<<dim3(2048), blk, 0, stream>>>(resid, nullptr, ln1w, ln1b, stats, nullptr, attn_h, attn_l);

  // ===== MHA2 (cross: KV from inputRes, Q from att_norm, no mask) =====
  p = {attn_h, attn_l, 1024, Wq2h, Wq2l, 0, 1024, 1024, nullptr, nullptr, nullptr, q_h, q_l};
  gemm3_k<1,0,3><<<g8, blk, 0, stream>>>(p);
  p = {IRh, IRl, 1024, Wk2h, Wk2l, 0, 1024, 1024, nullptr, nullptr, nullptr, k_h, k_l};
  gemm3_k<1,1,3><<<g8, blk, 0, stream>>>(p);
  p = {IRh, IRl, 1024, Wv2h, Wv2l, 0, 1024, 1024, nullptr, nullptr, nullptr, v_h, v_l};
  gemm3_k<1,5,3><<<g8, blk, 0, stream>>>(p);
  flash_k<0><<<dim3(16, 64), blk, 0, stream>>>(q_h, q_l, k_h, k_l, v_h, v_l, outr_h, outr_l);
  p = {outr_h, outr_l, 1024, Wo2h, Wo2l, 1024, 1024, 1024, OEf, nullptr, resid, nullptr, nullptr};
  gemm3_k<0,2,3><<<g8, blk, 0, stream>>>(p);
  ln_partial_k<<<dim3(128, 4), blk, 0, stream>>>(resid, nullptr, part);
  ln_final_k<<<dim3(4), dim3(64), 0, stream>>>(part, stats);
  ln_apply_k<1><<<dim3(2048), blk, 0, stream>>>(resid, nullptr, ln2w, ln2b, stats, att2n_f, a2n_h, a2n_l);

  // ===== FFN ((B,S,E)->(B,E,S) raw reshape is a flat no-op); 2-term split =====
  p = {a2n_h, a2n_l, 1024, W1h, W1l, 2048, 1024, 2048, nullptr, b1f, nullptr, hid_h, hid_l};
  gemm3_k<0,3,2><<<g16, blk, 0, stream>>>(p);
  p = {hid_h, hid_l, 2048, W2h, W2l, 1024, 2048, 1024, nullptr, b2f, fc, nullptr, nullptr};
  gemm3_k<0,4,2><<<g8, blk, 0, stream>>>(p);
  ln_partial_k<<<dim3(128, 4), blk, 0, stream>>>(fc, att2n_f, part);
  ln_final_k<<<dim3(4), dim3(64), 0, stream>>>(part, stats);
  ln_apply_k<2><<<dim3(2048), blk, 0, stream>>>(fc, att2n_f, ln3w, ln3b, stats, dout, nullptr, nullptr);
}

// Round 4
// 1025.217 us; speedup vs baseline: 1.2816x; 1.1335x over previous
//
#include <hip/hip_runtime.h>
#include <cstdint>
#include <cstddef>

// ============================================================================
// transformer_11441792877290 — MI355X fp32, round 4
// B=4 S=1024 E=1024 H=16 DK=64 FF=2048, SCALE=8, EPS=1e-5
// vs round 3 (passed, 1162us, absmax 0.1016):
//  * all weights pre-transposed to [N][K] bf16 hi/lo planes (batched LDS
//    transpose) -> GEMM B-frags are ds_read_b128 rows, zero unpack VALU
//  * QKV1 merged into one N=3072 GEMM, KV2 into one N=2048 GEMM
//  * flash: Q-tile pairing (sp, 15-sp): causal perfectly balanced at 17
//    MFMA-iters/block; K/V staged once for both Q-states; XCD swizzle
// ============================================================================

#define DI __device__ __forceinline__
#define MFMA __builtin_amdgcn_mfma_f32_16x16x32_bf16

typedef short s8v __attribute__((ext_vector_type(8)));
typedef float f4v __attribute__((ext_vector_type(4)));
typedef unsigned u4v __attribute__((ext_vector_type(4)));

DI float bf2f(short u){
  union { unsigned int i; float f; } v;
  v.i = ((unsigned int)(unsigned short)u) << 16;
  return v.f;
}
DI short f2bf(float f){  // round-to-nearest-even
  union { float f; unsigned int i; } v; v.f = f;
  unsigned int x = v.i;
  return (short)((x + 0x7fffu + ((x >> 16) & 1u)) >> 16);
}
DI unsigned pack2(short hi, short lo){
  return ((unsigned)(unsigned short)lo << 16) | (unsigned)(unsigned short)hi;
}

// ---------------------------------------------------------------------------
// fp32 -> bf16 hi/lo plane split (OE, IR)
// ---------------------------------------------------------------------------
struct SplitP { const float* src[2]; short* hi[2]; short* lo[2]; };

__launch_bounds__(256)
__global__ void splitall_k(SplitP sp){
  const int t = blockIdx.y;
  int i = (blockIdx.x * 256 + threadIdx.x) << 2;
  float4 v = *(const float4*)(sp.src[t] + i);
  float xs[4] = {v.x, v.y, v.z, v.w};
  short h[4], l[4];
  #pragma unroll
  for (int c = 0; c < 4; c++){
    h[c] = f2bf(xs[c]);
    l[c] = f2bf(xs[c] - bf2f(h[c]));
  }
  *(short4*)(sp.hi[t] + i) = make_short4(h[0], h[1], h[2], h[3]);
  *(short4*)(sp.lo[t] + i) = make_short4(l[0], l[1], l[2], l[3]);
}

// ---------------------------------------------------------------------------
// Batched weight transpose: fp32 [K][N] (or [H][E][DK] qkv gather) ->
// bf16 hi/lo planes [N][K]. 64x64 tiles via LDS.
// ---------------------------------------------------------------------------
struct TransP {
  const float* src[10];
  short* oh[10]; short* ol[10];
  int Kd[10]; int Nd[10]; int qkv[10]; int ntiles[10];
};

__launch_bounds__(256)
__global__ void transall_k(TransP tp){
  const int t = blockIdx.y;
  const int tile = blockIdx.x;
  if (tile >= tp.ntiles[t]) return;
  const int K = tp.Kd[t], N = tp.Nd[t];
  const int ncols = N >> 6;
  const int n0 = (tile % ncols) << 6, k0 = (tile / ncols) << 6;
  __shared__ float Ld[64 * 65];
  const int tid = threadIdx.x;
  const int row = tid >> 2, c16 = (tid & 3) << 4;
  const float* s = tp.src[t];
  size_t base;
  if (tp.qkv[t]) base = ((size_t)(n0 >> 6) << 16) + ((size_t)(k0 + row) << 6) + c16;
  else           base = (size_t)(k0 + row) * N + n0 + c16;
  #pragma unroll
  for (int j4 = 0; j4 < 4; j4++){
    float4 v = *(const float4*)(s + base + (j4 << 2));
    int c = row * 65 + c16 + (j4 << 2);
    Ld[c] = v.x; Ld[c + 1] = v.y; Ld[c + 2] = v.z; Ld[c + 3] = v.w;
  }
  __syncthreads();
  const int n = tid >> 2;
  s8v h0, h1, l0, l1;
  #pragma unroll
  for (int j = 0; j < 8; j++){
    float a = Ld[(c16 + j) * 65 + n];
    float b = Ld[(c16 + 8 + j) * 65 + n];
    short ha = f2bf(a), hb = f2bf(b);
    h0[j] = ha; l0[j] = f2bf(a - bf2f(ha));
    h1[j] = hb; l1[j] = f2bf(b - bf2f(hb));
  }
  size_t ob = (size_t)(n0 + n) * K + k0 + c16;
  *(s8v*)(tp.oh[t] + ob)     = h0;
  *(s8v*)(tp.oh[t] + ob + 8) = h1;
  *(s8v*)(tp.ol[t] + ob)     = l0;
  *(s8v*)(tp.ol[t] + ob + 8) = l1;
}

// ---------------------------------------------------------------------------
// Split-bf16 GEMM: C[M,N] = (Ah+Al)[M,K] x (Bh+Bl)[K,N], B given as B^T[N][K].
// TERMS=3: hh+hl+lh ; TERMS=2: hh+hl. Tile 128x128, BK=32, 4 waves. M=4096.
// All LDS traffic ds_read/write_b128, two separate planes per operand.
// EPI 0: hi/lo scatter q layout        2: fp32 = acc + xres
//     3: hi/lo planes = relu(acc+bias) 4: fp32 = acc + bias
//     6: QKV combined (seg0 q / seg1 K2^T / seg2 V^T)
//     7: KV combined  (seg0 K2^T / seg1 V^T)
// ---------------------------------------------------------------------------
struct GemmP {
  const short* Ah; const short* Al; int lda;
  const short* Bh; const short* Bl; int ldb;
  int K; int N;
  const float* xres; const float* bias;
  float* outf;
  short* o1h; short* o1l; short* o2h; short* o2l; short* o3h; short* o3l;
};

template<int EPI, int TERMS>
__launch_bounds__(256, 3)
__global__ void gemm_k(GemmP p){
  __shared__ short Ash[128 * 40];
  __shared__ short Asl[128 * 40];
  __shared__ short Bsh[128 * 40];
  __shared__ short Bsl[128 * 40];
  const int tid = threadIdx.x;
  const int L = tid & 63, w = tid >> 6;
  const int lr = L & 15, lg = L >> 4;
  const int mo = (w >> 1) << 6, no = (w & 1) << 6;
  const int m0 = blockIdx.y << 7, n0 = blockIdx.x << 7;

  f4v acc[4][4];
  #pragma unroll
  for (int i = 0; i < 4; i++)
    #pragma unroll
    for (int j = 0; j < 4; j++)
      #pragma unroll
      for (int r = 0; r < 4; r++) acc[i][j][r] = 0.0f;

  const int nkt = p.K >> 5;
  for (int kt = 0; kt < nkt; kt++){
    const int k0 = kt << 5;
    #pragma unroll
    for (int i = 0; i < 2; i++){
      int c = tid + (i << 8);            // 0..511
      int row = c >> 2, col8 = (c & 3) << 3;
      size_t offa = (size_t)(m0 + row) * p.lda + k0 + col8;
      *(s8v*)&Ash[row * 40 + col8] = *(const s8v*)(p.Ah + offa);
      *(s8v*)&Asl[row * 40 + col8] = *(const s8v*)(p.Al + offa);
      size_t offb = (size_t)(n0 + row) * p.ldb + k0 + col8;
      *(s8v*)&Bsh[row * 40 + col8] = *(const s8v*)(p.Bh + offb);
      *(s8v*)&Bsl[row * 40 + col8] = *(const s8v*)(p.Bl + offb);
    }
    __syncthreads();
    const int kbd = lg << 3;
    s8v a_h[4], a_l[4];
    #pragma unroll
    for (int mi = 0; mi < 4; mi++){
      const int row = mo + (mi << 4) + lr;
      a_h[mi] = *(const s8v*)&Ash[row * 40 + kbd];
      a_l[mi] = *(const s8v*)&Asl[row * 40 + kbd];
    }
    #pragma unroll
    for (int ni = 0; ni < 4; ni++){
      const int n = no + (ni << 4) + lr;
      s8v b_h = *(const s8v*)&Bsh[n * 40 + kbd];
      s8v b_l = *(const s8v*)&Bsl[n * 40 + kbd];
      #pragma unroll
      for (int mi = 0; mi < 4; mi++){
        acc[mi][ni] = MFMA(a_h[mi], b_h, acc[mi][ni], 0, 0, 0);
        acc[mi][ni] = MFMA(a_h[mi], b_l, acc[mi][ni], 0, 0, 0);
        if (TERMS == 3)
          acc[mi][ni] = MFMA(a_l[mi], b_h, acc[mi][ni], 0, 0, 0);
      }
    }
    __syncthreads();
  }

  // ---- epilogue (C/D map: col = lane&15, row = (lane>>4)*4 + reg)
  #pragma unroll
  for (int mi = 0; mi < 4; mi++){
    #pragma unroll
    for (int ni = 0; ni < 4; ni++){
      #pragma unroll
      for (int r = 0; r < 4; r++){
        float val = acc[mi][ni][r];
        int m = m0 + mo + (mi << 4) + (lg << 2) + r;
        int n = n0 + no + (ni << 4) + lr;
        if (EPI == 2){
          size_t o = (size_t)m * p.N + n;
          p.outf[o] = val + p.xres[o];
        } else if (EPI == 4){
          p.outf[(size_t)m * p.N + n] = val + p.bias[n];
        } else if (EPI == 3){
          float x = val + p.bias[n];
          x = x > 0.0f ? x : 0.0f;
          size_t o = (size_t)m * p.N + n;
          short hi = f2bf(x);
          p.o1h[o] = hi;
          p.o1l[o] = f2bf(x - bf2f(hi));
        } else {
          // scatter epilogues: EPI 0 (q), 6 (q/K2^T/V^T), 7 (K2^T/V^T)
          int seg = (EPI == 0) ? 0 : (n >> 10);
          int n1 = (EPI == 0) ? n : (n & 1023);
          int kind = (EPI == 0) ? 0 : (EPI == 6 ? seg : seg + 1);
          int b = m >> 10, s = m & 1023, hh = n1 >> 6, d = n1 & 63;
          size_t hb16 = (size_t)((hh << 2) | b) << 16;
          size_t dst;
          if (kind == 0)      dst = hb16 + ((size_t)s << 6) + d;
          else if (kind == 1) dst = hb16 + ((size_t)(((s & 15) << 6) | d) << 6) + (s >> 4);
          else                dst = hb16 + ((size_t)d << 10) + s;
          short *dh, *dl;
          if (EPI == 0){ dh = p.o1h; dl = p.o1l; }
          else if (EPI == 6){
            dh = seg == 0 ? p.o1h : (seg == 1 ? p.o2h : p.o3h);
            dl = seg == 0 ? p.o1l : (seg == 1 ? p.o2l : p.o3l);
          } else {
            dh = seg == 0 ? p.o1h : p.o2h;
            dl = seg == 0 ? p.o1l : p.o2l;
          }
          short hi = f2bf(val);
          dh[dst] = hi;
          dl[dst] = f2bf(val - bf2f(hi));
        }
      }
    }
  }
}

// ---------------------------------------------------------------------------
// Flash attention, paired Q-tiles. Per (h,b): Q[1024,64] x K2[64,1024]
// -> softmax/8 -> x V. K as K2^T[hb][t][dd], V as V^T[hb][d][s].
// Block owns Q-tiles (sp, 15-sp) [causal] or (sp, sp+8) [cross]: K/V staged
// once per tile for both states; causal perfectly balanced (17 iters/block).
// XCD swizzle: same-hb blocks share flat%8.
// ---------------------------------------------------------------------------
template<int CAUSAL>
__launch_bounds__(256, 2)
__global__ void flash_k(const short* __restrict__ qhi, const short* __restrict__ qlo,
                        const short* __restrict__ khi, const short* __restrict__ klo,
                        const short* __restrict__ vhi, const short* __restrict__ vlo,
                        short* __restrict__ ohi_g, short* __restrict__ olo_g){
  __shared__ short Kt[2][64*72];       // [t_local][dd]
  __shared__ short Vt[2][64*72];       // [d][t_local]
  __shared__ unsigned Ps[2][4][16*68]; // per-state, per-wave packed P
  const int tid = threadIdx.x, L = tid & 63, w = tid >> 6;
  const int lr = L & 15, lg = L >> 4;
  const int flat = blockIdx.x + (blockIdx.y << 3);       // grid (8,64)
  const int hb = ((flat & 7) << 3) | ((flat >> 3) & 7);  // same hb -> same XCD
  const int sp = flat >> 6;                              // 0..7
  const int h = hb >> 2, b = hb & 3;
  const size_t hbo = (size_t)hb << 16;
  const float NEG_INF = -__builtin_inff();
  int qt[2]; qt[0] = sp; qt[1] = CAUSAL ? (15 - sp) : (sp + 8);

  s8v qfh[2][2], qfl[2][2];
  #pragma unroll
  for (int st = 0; st < 2; st++){
    const size_t qoff = hbo + (size_t)((qt[st] << 6) + (w << 4) + lr) * 64 + (lg << 3);
    qfh[st][0] = *(const s8v*)(qhi + qoff);  qfh[st][1] = *(const s8v*)(qhi + qoff + 32);
    qfl[st][0] = *(const s8v*)(qlo + qoff);  qfl[st][1] = *(const s8v*)(qlo + qoff + 32);
  }

  f4v o[2][4];
  float mprev[2][4], lsum[2][4];
  #pragma unroll
  for (int st = 0; st < 2; st++){
    #pragma unroll
    for (int ni = 0; ni < 4; ni++)
      #pragma unroll
      for (int r = 0; r < 4; r++) o[st][ni][r] = 0.0f;
    #pragma unroll
    for (int r = 0; r < 4; r++){ mprev[st][r] = NEG_INF; lsum[st][r] = 0.0f; }
  }

  const int ntt = CAUSAL ? (qt[1] + 1) : 16;
  for (int ti = 0; ti < ntt; ti++){
    const int t0 = ti << 6;
    const bool actA = !(CAUSAL && ti > qt[0]);
    __syncthreads();
    #pragma unroll
    for (int i = 0; i < 8; i++){
      int c = tid + (i << 8);
      int buf = c >> 9, cc = c & 511, row = cc >> 3, col8 = (cc & 7) << 3;
      const short* g; short* dst;
      if      (buf == 0){ g = khi + hbo + ((size_t)t0 << 6) + ((size_t)cc << 3); dst = &Kt[0][row*72 + col8]; }
      else if (buf == 1){ g = klo + hbo + ((size_t)t0 << 6) + ((size_t)cc << 3); dst = &Kt[1][row*72 + col8]; }
      else if (buf == 2){ g = vhi + hbo + ((size_t)row << 10) + t0 + col8;       dst = &Vt[0][row*72 + col8]; }
      else              { g = vlo + hbo + ((size_t)row << 10) + t0 + col8;       dst = &Vt[1][row*72 + col8]; }
      *(s8v*)dst = *(const s8v*)g;
    }
    __syncthreads();

    // ---- QK for both states; K-frags loaded once
    f4v sa[2][4];
    #pragma unroll
    for (int st = 0; st < 2; st++)
      #pragma unroll
      for (int ni = 0; ni < 4; ni++)
        #pragma unroll
        for (int r = 0; r < 4; r++) sa[st][ni][r] = 0.0f;
    #pragma unroll
    for (int ks = 0; ks < 2; ks++){
      const int kb = (ks << 5) + (lg << 3);
      #pragma unroll
      for (int ni = 0; ni < 4; ni++){
        const int tl = (ni << 4) + lr;
        s8v kbh = *(const s8v*)&Kt[0][tl * 72 + kb];
        s8v kbl = *(const s8v*)&Kt[1][tl * 72 + kb];
        if (actA){
          sa[0][ni] = MFMA(qfh[0][ks], kbh, sa[0][ni], 0, 0, 0);
          sa[0][ni] = MFMA(qfh[0][ks], kbl, sa[0][ni], 0, 0, 0);
          sa[0][ni] = MFMA(qfl[0][ks], kbh, sa[0][ni], 0, 0, 0);
        }
        sa[1][ni] = MFMA(qfh[1][ks], kbh, sa[1][ni], 0, 0, 0);
        sa[1][ni] = MFMA(qfh[1][ks], kbl, sa[1][ni], 0, 0, 0);
        sa[1][ni] = MFMA(qfl[1][ks], kbh, sa[1][ni], 0, 0, 0);
      }
    }

    // ---- softmax + P write per state
    #pragma unroll
    for (int st = 0; st < 2; st++){
      if (st == 0 && !actA) continue;
      const int s0w = (qt[st] << 6) + (w << 4);
      const bool diag = CAUSAL && (ti == qt[st]);
      float tm[4] = {NEG_INF, NEG_INF, NEG_INF, NEG_INF};
      #pragma unroll
      for (int ni = 0; ni < 4; ni++)
        #pragma unroll
        for (int r = 0; r < 4; r++){
          float v = sa[st][ni][r] * 0.125f;
          if (diag){
            int tg = t0 + (ni << 4) + lr;
            int sg = s0w + (lg << 2) + r;
            if (tg > sg) v = NEG_INF;
          }
          sa[st][ni][r] = v;
          tm[r] = fmaxf(tm[r], v);
        }
      #pragma unroll
      for (int off = 1; off < 16; off <<= 1)
        #pragma unroll
        for (int r = 0; r < 4; r++) tm[r] = fmaxf(tm[r], __shfl_xor(tm[r], off, 16));
      float alpha[4], psum[4];
      #pragma unroll
      for (int r = 0; r < 4; r++){
        float mn = fmaxf(mprev[st][r], tm[r]);
        alpha[r] = __expf(mprev[st][r] - mn);
        mprev[st][r] = mn;
        psum[r] = 0.0f;
      }
      #pragma unroll
      for (int ni = 0; ni < 4; ni++)
        #pragma unroll
        for (int r = 0; r < 4; r++){
          float pv = __expf(sa[st][ni][r] - mprev[st][r]);
          sa[st][ni][r] = pv;
          psum[r] += pv;
        }
      #pragma unroll
      for (int off = 1; off < 16; off <<= 1)
        #pragma unroll
        for (int r = 0; r < 4; r++) psum[r] += __shfl_xor(psum[r], off, 16);
      #pragma unroll
      for (int r = 0; r < 4; r++) lsum[st][r] = lsum[st][r] * alpha[r] + psum[r];
      #pragma unroll
      for (int ni = 0; ni < 4; ni++)
        #pragma unroll
        for (int r = 0; r < 4; r++) o[st][ni][r] *= alpha[r];
      #pragma unroll
      for (int ni = 0; ni < 4; ni++)
        #pragma unroll
        for (int r = 0; r < 4; r++){
          int prow = (lg << 2) + r, pcol = (ni << 4) + lr;
          float pv = sa[st][ni][r];
          short hi = f2bf(pv);
          Ps[st][w][prow * 68 + pcol] = pack2(hi, f2bf(pv - bf2f(hi)));
        }
    }

    // ---- PV for both states; V-frags loaded once (same-wave LDS RAW order)
    #pragma unroll
    for (int ks = 0; ks < 2; ks++){
      const int kb = (ks << 5) + (lg << 3);
      s8v ph[2], pl[2];
      #pragma unroll
      for (int st = 0; st < 2; st++){
        if (st == 0 && !actA) continue;
        u4v p0 = *(const u4v*)&Ps[st][w][lr * 68 + kb];
        u4v p1 = *(const u4v*)&Ps[st][w][lr * 68 + kb + 4];
        #pragma unroll
        for (int j = 0; j < 4; j++){
          ph[st][j]     = (short)(p0[j] & 0xffffu);  pl[st][j]     = (short)(p0[j] >> 16);
          ph[st][4 + j] = (short)(p1[j] & 0xffffu);  pl[st][4 + j] = (short)(p1[j] >> 16);
        }
      }
      #pragma unroll
      for (int ni = 0; ni < 4; ni++){
        const int d = (ni << 4) + lr;
        s8v vbh = *(const s8v*)&Vt[0][d * 72 + kb];
        s8v vbl = *(const s8v*)&Vt[1][d * 72 + kb];
        if (actA){
          o[0][ni] = MFMA(ph[0], vbh, o[0][ni], 0, 0, 0);
          o[0][ni] = MFMA(ph[0], vbl, o[0][ni], 0, 0, 0);
          o[0][ni] = MFMA(pl[0], vbh, o[0][ni], 0, 0, 0);
        }
        o[1][ni] = MFMA(ph[1], vbh, o[1][ni], 0, 0, 0);
        o[1][ni] = MFMA(ph[1], vbl, o[1][ni], 0, 0, 0);
        o[1][ni] = MFMA(pl[1], vbh, o[1][ni], 0, 0, 0);
      }
    }
  }

  // ---- normalize, scatter to raw head-concat reshape layout (both states)
  #pragma unroll
  for (int st = 0; st < 2; st++){
    const int s0w = (qt[st] << 6) + (w << 4);
    #pragma unroll
    for (int ni = 0; ni < 4; ni++){
      #pragma unroll
      for (int r = 0; r < 4; r++){
        float val = o[st][ni][r] / lsum[st][r];
        int s = s0w + (lg << 2) + r;
        int d = (ni << 4) + lr;
        int s2i = ((h & 3) << 8) | (b << 6) | (s >> 4);
        int c   = ((s & 15) << 6) | d;
        size_t dst = ((size_t)(h >> 2) << 20) + ((size_t)s2i << 10) + c;
        short hi = f2bf(val);
        ohi_g[dst] = hi;
        olo_g[dst] = f2bf(val - bf2f(hi));
      }
    }
  }
}

// ---------------------------------------------------------------------------
// LayerNorm over (S,E) = 1M elems per batch, three-stage.
// ---------------------------------------------------------------------------
__launch_bounds__(256)
__global__ void ln_partial_k(const float* s1, const float* s2, float2* part){
  const int tid = threadIdx.x, L = tid & 63, w = tid >> 6;
  const int b = blockIdx.y, j = blockIdx.x;
  const size_t base = ((size_t)b << 20) + ((size_t)j << 13) + ((size_t)tid << 2);
  float sum = 0.0f, ss = 0.0f;
  #pragma unroll
  for (int i = 0; i < 8; i++){
    size_t idx = base + ((size_t)i << 10);
    float4 v = *(const float4*)(s1 + idx);
    if (s2){
      float4 u = *(const float4*)(s2 + idx);
      v.x += u.x; v.y += u.y; v.z += u.z; v.w += u.w;
    }
    sum += v.x + v.y + v.z + v.w;
    ss  += v.x*v.x + v.y*v.y + v.z*v.z + v.w*v.w;
  }
  #pragma unroll
  for (int off = 1; off < 64; off <<= 1){
    sum += __shfl_xor(sum, off, 64);
    ss  += __shfl_xor(ss,  off, 64);
  }
  __shared__ float red[4][2];
  if (L == 0){ red[w][0] = sum; red[w][1] = ss; }
  __syncthreads();
  if (tid == 0){
    float s_ = red[0][0] + red[1][0] + red[2][0] + red[3][0];
    float q_ = red[0][1] + red[1][1] + red[2][1] + red[3][1];
    part[b * 128 + j] = make_float2(s_, q_);
  }
}

__launch_bounds__(64)
__global__ void ln_final_k(const float2* part, float2* stats){
  const int b = blockIdx.x, t = threadIdx.x;
  float2 a = part[b * 128 + t], c = part[b * 128 + 64 + t];
  float sum = a.x + c.x, ss = a.y + c.y;
  #pragma unroll
  for (int off = 1; off < 64; off <<= 1){
    sum += __shfl_xor(sum, off, 64);
    ss  += __shfl_xor(ss,  off, 64);
  }
  if (t == 0){
    float mean = sum * (1.0f / 1048576.0f);
    float var  = ss  * (1.0f / 1048576.0f) - mean * mean;
    stats[b] = make_float2(mean, rsqrtf(var + 1e-5f));
  }
}

// MODE 0: hi/lo planes | MODE 1: fp32 + hi/lo planes | MODE 2: fp32 out only
template<int MODE>
__launch_bounds__(256)
__global__ void ln_apply_k(const float* s1, const float* s2,
                           const float* wgt, const float* bias,
                           const float2* stats,
                           float* dstf, short* dsta, short* dstb){
  const int tid = threadIdx.x;
  const size_t base = ((size_t)blockIdx.x << 11) + ((size_t)tid << 2);
  #pragma unroll
  for (int i = 0; i < 2; i++){
    size_t idx = base + ((size_t)i << 10);
    int b = (int)(idx >> 20);
    float2 st = stats[b];
    float4 x = *(const float4*)(s1 + idx);
    if (s2){
      float4 u = *(const float4*)(s2 + idx);
      x.x += u.x; x.y += u.y; x.z += u.z; x.w += u.w;
    }
    unsigned wi = (unsigned)(idx & 1048575u);
    float4 wv = *(const float4*)(wgt + wi);
    float4 bv = *(const float4*)(bias + wi);
    float xv[4] = {x.x, x.y, x.z, x.w};
    float wvv[4] = {wv.x, wv.y, wv.z, wv.w};
    float bvv[4] = {bv.x, bv.y, bv.z, bv.w};
    float yv[4];
    #pragma unroll
    for (int c = 0; c < 4; c++)
      yv[c] = (xv[c] - st.x) * st.y * wvv[c] + bvv[c];
    if (MODE == 0 || MODE == 1){
      short h[4], l[4];
      #pragma unroll
      for (int c = 0; c < 4; c++){
        h[c] = f2bf(yv[c]);
        l[c] = f2bf(yv[c] - bf2f(h[c]));
      }
      *(short4*)(dsta + idx) = make_short4(h[0], h[1], h[2], h[3]);
      *(short4*)(dstb + idx) = make_short4(l[0], l[1], l[2], l[3]);
      if (MODE == 1)
        *(float4*)(dstf + idx) = make_float4(yv[0], yv[1], yv[2], yv[3]);
    } else {
      *(float4*)(dstf + idx) = make_float4(yv[0], yv[1], yv[2], yv[3]);
    }
  }
}

// ---------------------------------------------------------------------------
extern "C" void kernel_launch(void* const* d_in, const int* in_sizes, int n_in,
                              void* d_out, int out_size, void* d_ws, size_t ws_size,
                              hipStream_t stream){
  const float* IRf = (const float*)d_in[0];
  const float* OEf = (const float*)d_in[1];
  const float* Wq1f = (const float*)d_in[2];
  const float* Wk1f = (const float*)d_in[3];
  const float* Wv1f = (const float*)d_in[4];
  const float* Wo1f = (const float*)d_in[5];
  const float* Wq2f = (const float*)d_in[6];
  const float* Wk2f = (const float*)d_in[7];
  const float* Wv2f = (const float*)d_in[8];
  const float* Wo2f = (const float*)d_in[9];
  const float* ln1w = (const float*)d_in[10];
  const float* ln1b = (const float*)d_in[11];
  const float* ln2w = (const float*)d_in[12];
  const float* ln2b = (const float*)d_in[13];
  const float* ln3w = (const float*)d_in[14];
  const float* ln3b = (const float*)d_in[15];
  const float* W1f = (const float*)d_in[16];
  const float* b1f = (const float*)d_in[17];
  const float* W2f = (const float*)d_in[18];
  const float* b2f = (const float*)d_in[19];
  float* dout = (float*)d_out;

  char* ws = (char*)d_ws;
  const size_t MB = (size_t)1 << 20;
  short* OEh = (short*)(ws + 0*MB),  *OEl = (short*)(ws + 8*MB);
  short* IRh = (short*)(ws + 16*MB), *IRl = (short*)(ws + 24*MB);
  short* QKV1t_h = (short*)(ws + 32*MB), *QKV1t_l = (short*)(ws + 38*MB);  // [3072][1024]
  short* Wo1t_h  = (short*)(ws + 44*MB), *Wo1t_l  = (short*)(ws + 46*MB);  // [1024][1024]
  short* Q2t_h   = (short*)(ws + 48*MB), *Q2t_l   = (short*)(ws + 50*MB);
  short* KV2t_h  = (short*)(ws + 52*MB), *KV2t_l  = (short*)(ws + 56*MB);  // [2048][1024]
  short* Wo2t_h  = (short*)(ws + 60*MB), *Wo2t_l  = (short*)(ws + 62*MB);
  short* W1t_h   = (short*)(ws + 64*MB), *W1t_l   = (short*)(ws + 68*MB);  // [2048][1024]
  short* W2t_h   = (short*)(ws + 72*MB), *W2t_l   = (short*)(ws + 76*MB);  // [1024][2048]
  short* q_h = (short*)(ws + 80*MB),  *q_l = (short*)(ws + 88*MB);
  short* k_h = (short*)(ws + 96*MB),  *k_l = (short*)(ws + 104*MB);
  short* v_h = (short*)(ws + 112*MB), *v_l = (short*)(ws + 120*MB);
  short* outr_h = (short*)(ws + 128*MB), *outr_l = (short*)(ws + 136*MB);
  float* resid = (float*)(ws + 144*MB);
  short* attn_h = (short*)(ws + 160*MB), *attn_l = (short*)(ws + 168*MB);
  float* att2n_f = (float*)(ws + 176*MB);
  // aliases (dead ranges)
  short* hid_h = (short*)(ws + 80*MB);   // [4096][2048] over q planes
  short* hid_l = (short*)(ws + 96*MB);   // over k planes
  float* fc    = (float*)(ws + 112*MB);  // over v planes
  short* a2n_h = (short*)(ws + 160*MB);  // over attn planes
  short* a2n_l = (short*)(ws + 168*MB);
  float2* part  = (float2*)(ws + 192*MB);
  float2* stats = (float2*)(ws + 192*MB + 65536);

  dim3 blk(256);

  // ---- split OE/IR into bf16 hi/lo planes
  SplitP sp;
  sp.src[0] = OEf; sp.hi[0] = OEh; sp.lo[0] = OEl;
  sp.src[1] = IRf; sp.hi[1] = IRh; sp.lo[1] = IRl;
  splitall_k<<<dim3(4096, 2), blk, 0, stream>>>(sp);

  // ---- batched weight transpose to [N][K] hi/lo planes
  TransP tp;
  const float* tsrc[10] = {Wq1f, Wk1f, Wv1f, Wo1f, Wq2f, Wk2f, Wv2f, Wo2f, W1f, W2f};
  short* toh[10] = {QKV1t_h, QKV1t_h + (1<<20), QKV1t_h + (2<<20), Wo1t_h,
                    Q2t_h, KV2t_h, KV2t_h + (1<<20), Wo2t_h, W1t_h, W2t_h};
  short* tol[10] = {QKV1t_l, QKV1t_l + (1<<20), QKV1t_l + (2<<20), Wo1t_l,
                    Q2t_l, KV2t_l, KV2t_l + (1<<20), Wo2t_l, W1t_l, W2t_l};
  int tK[10]   = {1024,1024,1024,1024,1024,1024,1024,1024,1024,2048};
  int tN[10]   = {1024,1024,1024,1024,1024,1024,1024,1024,2048,1024};
  int tq[10]   = {1,1,1,0,1,1,1,0,0,0};
  int tt[10]   = {256,256,256,256,256,256,256,256,512,512};
  for (int i = 0; i < 10; i++){
    tp.src[i] = tsrc[i]; tp.oh[i] = toh[i]; tp.ol[i] = tol[i];
    tp.Kd[i] = tK[i]; tp.Nd[i] = tN[i]; tp.qkv[i] = tq[i]; tp.ntiles[i] = tt[i];
  }
  transall_k<<<dim3(512, 10), blk, 0, stream>>>(tp);

  GemmP p{};

  // ===== MHA1 (self, causal) =====
  p = {OEh, OEl, 1024, QKV1t_h, QKV1t_l, 1024, 1024, 3072, nullptr, nullptr,
       nullptr, q_h, q_l, k_h, k_l, v_h, v_l};
  gemm_k<6,3><<<dim3(24, 32), blk, 0, stream>>>(p);
  flash_k<1><<<dim3(8, 64), blk, 0, stream>>>(q_h, q_l, k_h, k_l, v_h, v_l, outr_h, outr_l);
  p = {outr_h, outr_l, 1024, Wo1t_h, Wo1t_l, 1024, 1024, 1024, OEf, nullptr,
       resid, nullptr, nullptr, nullptr, nullptr, nullptr, nullptr};
  gemm_k<2,3><<<dim3(8, 32), blk, 0, stream>>>(p);
  ln_partial_k<<<dim3(128, 4), blk, 0, stream>>>(resid, nullptr, part);
  ln_final_k<<<dim3(4), dim3(64), 0, stream>>>(part, stats);
  ln_apply_k<0><<<dim3(2048), blk, 0, stream>>>(resid, nullptr, ln1w, ln1b, stats, nullptr, attn_h, attn_l);

  // ===== MHA2 (cross: KV from inputRes, Q from att_norm, no mask) =====
  p = {attn_h, attn_l, 1024, Q2t_h, Q2t_l, 1024, 1024, 1024, nullptr, nullptr,
       nullptr, q_h, q_l, nullptr, nullptr, nullptr, nullptr};
  gemm_k<0,3><<<dim3(8, 32), blk, 0, stream>>>(p);
  p = {IRh, IRl, 1024, KV2t_h, KV2t_l, 1024, 1024, 2048, nullptr, nullptr,
       nullptr, k_h, k_l, v_h, v_l, nullptr, nullptr};
  gemm_k<7,3><<<dim3(16, 32), blk, 0, stream>>>(p);
  flash_k<0><<<dim3(8, 64), blk, 0, stream>>>(q_h, q_l, k_h, k_l, v_h, v_l, outr_h, outr_l);
  p = {outr_h, outr_l, 1024, Wo2t_h, Wo2t_l, 1024, 1024, 1024, OEf, nullptr,
       resid, nullptr, nullptr, nullptr, nullptr, nullptr, nullptr};
  gemm_k<2,3><<<dim3(8, 32), blk, 0, stream>>>(p);
  ln_partial_k<<<dim3(128, 4), blk, 0, stream>>>(resid, nullptr, part);
  ln_final_k<<<dim3(4), dim3(64), 0, stream>>>(part, stats);
  ln_apply_k<1><<<dim3(2048), blk, 0, stream>>>(resid, nullptr, ln2w, ln2b, stats, att2n_f, a2n_h, a2n_l);

  // ===== FFN ((B,S,E)->(B,E,S) raw reshape is a flat no-op); 2-term =====
  p = {a2n_h, a2n_l, 1024, W1t_h, W1t_l, 1024, 1024, 2048, nullptr, b1f,
       nullptr, hid_h, hid_l, nullptr, nullptr, nullptr, nullptr};
  gemm_k<3,2><<<dim3(16, 32), blk, 0, stream>>>(p);
  p = {hid_h, hid_l, 2048, W2t_h, W2t_l, 2048, 2048, 1024, nullptr, b2f,
       fc, nullptr, nullptr, nullptr, nullptr, nullptr, nullptr};
  gemm_k<4,2><<<dim3(8, 32), blk, 0, stream>>>(p);
  ln_partial_k<<<dim3(128, 4), blk, 0, stream>>>(fc, att2n_f, part);
  ln_final_k<<<dim3(4), dim3(64), 0, stream>>>(part, stats);
  ln_apply_k<2><<<dim3(2048), blk, 0, stream>>>(fc, att2n_f, ln3w, ln3b, stats, dout, nullptr, nullptr);
}

// Round 5
// 871.010 us; speedup vs baseline: 1.5085x; 1.1770x over previous
//
#include <hip/hip_runtime.h>
#include <cstdint>
#include <cstddef>

// ============================================================================
// transformer_11441792877290 — MI355X fp32, round 5
// B=4 S=1024 E=1024 H=16 DK=64 FF=2048, SCALE=8, EPS=1e-5
// vs round 4 (passed, 1025us, absmax 0.1016):
//  * GEMM K-loop restructured: async double-buffered staging via
//    global_load_lds width=16 (un-padded stride-32 LDS planes, lane-contig);
//    one barrier/iter; frag ds_reads precede the next-tile issue so the
//    prefetch overlaps the 48-MFMA compute phase (fixes the 5800-cyc/iter
//    latency exposure seen at 1 block/CU).
//  * XCD-aware block swizzle: f%8 = XCD, n fastest within XCD at fixed
//    m-block -> each A row-block L2-resident on exactly one XCD.
// ============================================================================

#define DI __device__ __forceinline__
#define MFMA __builtin_amdgcn_mfma_f32_16x16x32_bf16

typedef short s8v __attribute__((ext_vector_type(8)));
typedef float f4v __attribute__((ext_vector_type(4)));
typedef unsigned u4v __attribute__((ext_vector_type(4)));

DI float bf2f(short u){
  union { unsigned int i; float f; } v;
  v.i = ((unsigned int)(unsigned short)u) << 16;
  return v.f;
}
DI short f2bf(float f){  // round-to-nearest-even
  union { float f; unsigned int i; } v; v.f = f;
  unsigned int x = v.i;
  return (short)((x + 0x7fffu + ((x >> 16) & 1u)) >> 16);
}
DI unsigned pack2(short hi, short lo){
  return ((unsigned)(unsigned short)lo << 16) | (unsigned)(unsigned short)hi;
}
DI void gload16(const void* g, void* l){
  __builtin_amdgcn_global_load_lds(
      (const __attribute__((address_space(1))) unsigned*)g,
      (__attribute__((address_space(3))) unsigned*)l, 16, 0, 0);
}

// ---------------------------------------------------------------------------
// fp32 -> bf16 hi/lo plane split (OE, IR)
// ---------------------------------------------------------------------------
struct SplitP { const float* src[2]; short* hi[2]; short* lo[2]; };

__launch_bounds__(256)
__global__ void splitall_k(SplitP sp){
  const int t = blockIdx.y;
  int i = (blockIdx.x * 256 + threadIdx.x) << 2;
  float4 v = *(const float4*)(sp.src[t] + i);
  float xs[4] = {v.x, v.y, v.z, v.w};
  short h[4], l[4];
  #pragma unroll
  for (int c = 0; c < 4; c++){
    h[c] = f2bf(xs[c]);
    l[c] = f2bf(xs[c] - bf2f(h[c]));
  }
  *(short4*)(sp.hi[t] + i) = make_short4(h[0], h[1], h[2], h[3]);
  *(short4*)(sp.lo[t] + i) = make_short4(l[0], l[1], l[2], l[3]);
}

// ---------------------------------------------------------------------------
// Batched weight transpose: fp32 [K][N] (or [H][E][DK] qkv gather) ->
// bf16 hi/lo planes [N][K]. 64x64 tiles via LDS.
// ---------------------------------------------------------------------------
struct TransP {
  const float* src[10];
  short* oh[10]; short* ol[10];
  int Kd[10]; int Nd[10]; int qkv[10]; int ntiles[10];
};

__launch_bounds__(256)
__global__ void transall_k(TransP tp){
  const int t = blockIdx.y;
  const int tile = blockIdx.x;
  if (tile >= tp.ntiles[t]) return;
  const int K = tp.Kd[t], N = tp.Nd[t];
  const int ncols = N >> 6;
  const int n0 = (tile % ncols) << 6, k0 = (tile / ncols) << 6;
  __shared__ float Ld[64 * 65];
  const int tid = threadIdx.x;
  const int row = tid >> 2, c16 = (tid & 3) << 4;
  const float* s = tp.src[t];
  size_t base;
  if (tp.qkv[t]) base = ((size_t)(n0 >> 6) << 16) + ((size_t)(k0 + row) << 6) + c16;
  else           base = (size_t)(k0 + row) * N + n0 + c16;
  #pragma unroll
  for (int j4 = 0; j4 < 4; j4++){
    float4 v = *(const float4*)(s + base + (j4 << 2));
    int c = row * 65 + c16 + (j4 << 2);
    Ld[c] = v.x; Ld[c + 1] = v.y; Ld[c + 2] = v.z; Ld[c + 3] = v.w;
  }
  __syncthreads();
  const int n = tid >> 2;
  s8v h0, h1, l0, l1;
  #pragma unroll
  for (int j = 0; j < 8; j++){
    float a = Ld[(c16 + j) * 65 + n];
    float b = Ld[(c16 + 8 + j) * 65 + n];
    short ha = f2bf(a), hb = f2bf(b);
    h0[j] = ha; l0[j] = f2bf(a - bf2f(ha));
    h1[j] = hb; l1[j] = f2bf(b - bf2f(hb));
  }
  size_t ob = (size_t)(n0 + n) * K + k0 + c16;
  *(s8v*)(tp.oh[t] + ob)     = h0;
  *(s8v*)(tp.oh[t] + ob + 8) = h1;
  *(s8v*)(tp.ol[t] + ob)     = l0;
  *(s8v*)(tp.ol[t] + ob + 8) = l1;
}

// ---------------------------------------------------------------------------
// Split-bf16 GEMM: C[M,N] = (Ah+Al)[M,K] x (Bh+Bl)[K,N], B given as B^T[N][K].
// TERMS=3: hh+hl+lh ; TERMS=2: hh+hl. Tile 128x128, BK=32, 4 waves. M=4096.
// Async double-buffered staging (global_load_lds w16); stride-32 LDS planes
// (un-padded: lane-contiguous as required); wave w stages plane w.
// XCD swizzle: f%8=xcd, n fastest within xcd.
// EPI 0: hi/lo scatter q layout        2: fp32 = acc + xres
//     3: hi/lo planes = relu(acc+bias) 4: fp32 = acc + bias
//     6: QKV combined (seg0 q / seg1 K2^T / seg2 V^T)
//     7: KV combined  (seg0 K2^T / seg1 V^T)
// ---------------------------------------------------------------------------
struct GemmP {
  const short* Ah; const short* Al; int lda;
  const short* Bh; const short* Bl; int ldb;
  int K; int N;
  const float* xres; const float* bias;
  float* outf;
  short* o1h; short* o1l; short* o2h; short* o2l; short* o3h; short* o3l;
};

template<int EPI, int TERMS>
__launch_bounds__(256, 2)
__global__ void gemm_k(GemmP p){
  __shared__ short Ash[2][4096];   // [buf][128*32] stride 32
  __shared__ short Asl[2][4096];
  __shared__ short Bsh[2][4096];
  __shared__ short Bsl[2][4096];
  const int tid = threadIdx.x;
  const int L = tid & 63, w = tid >> 6;
  const int lr = L & 15, lg = L >> 4;
  const int mo = (w >> 1) << 6, no = (w & 1) << 6;

  // ---- XCD swizzle: flat%8 = xcd; within xcd, n varies fastest
  const int gx = gridDim.x, gy = gridDim.y;
  const int f = blockIdx.y * gx + blockIdx.x;
  const int j = f >> 3;
  const int jm = j / gx;
  const int mb = (f & 7) * (gy >> 3) + jm;
  const int nb = j - jm * gx;
  const int m0 = mb << 7, n0 = nb << 7;

  // ---- per-wave staging setup: wave w owns one plane; lane L covers
  // row = i*16 + (L>>2), col8 = (L&3)*8; LDS byte = L*16 (+ i*1024)
  const int lrow = L >> 2, lcol = (L & 3) << 3;
  const short* gp0;
  size_t gstr;
  if      (w == 0){ gp0 = p.Ah + (size_t)(m0 + lrow) * p.lda + lcol; gstr = (size_t)p.lda << 4; }
  else if (w == 1){ gp0 = p.Al + (size_t)(m0 + lrow) * p.lda + lcol; gstr = (size_t)p.lda << 4; }
  else if (w == 2){ gp0 = p.Bh + (size_t)(n0 + lrow) * p.ldb + lcol; gstr = (size_t)p.ldb << 4; }
  else            { gp0 = p.Bl + (size_t)(n0 + lrow) * p.ldb + lcol; gstr = (size_t)p.ldb << 4; }

  f4v acc[4][4];
  #pragma unroll
  for (int i = 0; i < 4; i++)
    #pragma unroll
    for (int jj = 0; jj < 4; jj++)
      #pragma unroll
      for (int r = 0; r < 4; r++) acc[i][jj][r] = 0.0f;

  const int nkt = p.K >> 5;

  // prologue: stage tile 0 into buf 0
  {
    short* lp = (w == 0) ? &Ash[0][0] : (w == 1) ? &Asl[0][0] : (w == 2) ? &Bsh[0][0] : &Bsl[0][0];
    #pragma unroll
    for (int i = 0; i < 8; i++) gload16(gp0 + (size_t)i * gstr, lp + i * 512);
  }

  for (int kt = 0; kt < nkt; kt++){
    const int cur = kt & 1;
    __syncthreads();   // drains vmcnt: tile kt landed; prev readers of buf cur^1 done

    // ---- read all fragments for this tile into registers FIRST
    const int kbd = lg << 3;
    s8v a_h[4], a_l[4], b_h[4], b_l[4];
    #pragma unroll
    for (int mi = 0; mi < 4; mi++){
      const int row = mo + (mi << 4) + lr;
      a_h[mi] = *(const s8v*)&Ash[cur][(row << 5) + kbd];
      a_l[mi] = *(const s8v*)&Asl[cur][(row << 5) + kbd];
    }
    #pragma unroll
    for (int ni = 0; ni < 4; ni++){
      const int n = no + (ni << 4) + lr;
      b_h[ni] = *(const s8v*)&Bsh[cur][(n << 5) + kbd];
      b_l[ni] = *(const s8v*)&Bsl[cur][(n << 5) + kbd];
    }

    // ---- issue async prefetch of tile kt+1 into the other buffer
    if (kt + 1 < nkt){
      const int nxt = cur ^ 1;
      const short* gp = gp0 + ((kt + 1) << 5);
      short* lp = (w == 0) ? &Ash[nxt][0] : (w == 1) ? &Asl[nxt][0] : (w == 2) ? &Bsh[nxt][0] : &Bsl[nxt][0];
      #pragma unroll
      for (int i = 0; i < 8; i++) gload16(gp + (size_t)i * gstr, lp + i * 512);
    }

    // ---- MFMAs (overlap the in-flight prefetch)
    #pragma unroll
    for (int ni = 0; ni < 4; ni++){
      #pragma unroll
      for (int mi = 0; mi < 4; mi++){
        acc[mi][ni] = MFMA(a_h[mi], b_h[ni], acc[mi][ni], 0, 0, 0);
        acc[mi][ni] = MFMA(a_h[mi], b_l[ni], acc[mi][ni], 0, 0, 0);
        if (TERMS == 3)
          acc[mi][ni] = MFMA(a_l[mi], b_h[ni], acc[mi][ni], 0, 0, 0);
      }
    }
  }

  // ---- epilogue (C/D map: col = lane&15, row = (lane>>4)*4 + reg)
  #pragma unroll
  for (int mi = 0; mi < 4; mi++){
    #pragma unroll
    for (int ni = 0; ni < 4; ni++){
      #pragma unroll
      for (int r = 0; r < 4; r++){
        float val = acc[mi][ni][r];
        int m = m0 + mo + (mi << 4) + (lg << 2) + r;
        int n = n0 + no + (ni << 4) + lr;
        if (EPI == 2){
          size_t o = (size_t)m * p.N + n;
          p.outf[o] = val + p.xres[o];
        } else if (EPI == 4){
          p.outf[(size_t)m * p.N + n] = val + p.bias[n];
        } else if (EPI == 3){
          float x = val + p.bias[n];
          x = x > 0.0f ? x : 0.0f;
          size_t o = (size_t)m * p.N + n;
          short hi = f2bf(x);
          p.o1h[o] = hi;
          p.o1l[o] = f2bf(x - bf2f(hi));
        } else {
          // scatter epilogues: EPI 0 (q), 6 (q/K2^T/V^T), 7 (K2^T/V^T)
          int seg = (EPI == 0) ? 0 : (n >> 10);
          int n1 = (EPI == 0) ? n : (n & 1023);
          int kind = (EPI == 0) ? 0 : (EPI == 6 ? seg : seg + 1);
          int b = m >> 10, s = m & 1023, hh = n1 >> 6, d = n1 & 63;
          size_t hb16 = (size_t)((hh << 2) | b) << 16;
          size_t dst;
          if (kind == 0)      dst = hb16 + ((size_t)s << 6) + d;
          else if (kind == 1) dst = hb16 + ((size_t)(((s & 15) << 6) | d) << 6) + (s >> 4);
          else                dst = hb16 + ((size_t)d << 10) + s;
          short *dh, *dl;
          if (EPI == 0){ dh = p.o1h; dl = p.o1l; }
          else if (EPI == 6){
            dh = seg == 0 ? p.o1h : (seg == 1 ? p.o2h : p.o3h);
            dl = seg == 0 ? p.o1l : (seg == 1 ? p.o2l : p.o3l);
          } else {
            dh = seg == 0 ? p.o1h : p.o2h;
            dl = seg == 0 ? p.o1l : p.o2l;
          }
          short hi = f2bf(val);
          dh[dst] = hi;
          dl[dst] = f2bf(val - bf2f(hi));
        }
      }
    }
  }
}

// ---------------------------------------------------------------------------
// Flash attention, paired Q-tiles. Per (h,b): Q[1024,64] x K2[64,1024]
// -> softmax/8 -> x V. K as K2^T[hb][t][dd], V as V^T[hb][d][s].
// Block owns Q-tiles (sp, 15-sp) [causal] or (sp, sp+8) [cross].
// ---------------------------------------------------------------------------
template<int CAUSAL>
__launch_bounds__(256, 2)
__global__ void flash_k(const short* __restrict__ qhi, const short* __restrict__ qlo,
                        const short* __restrict__ khi, const short* __restrict__ klo,
                        const short* __restrict__ vhi, const short* __restrict__ vlo,
                        short* __restrict__ ohi_g, short* __restrict__ olo_g){
  __shared__ short Kt[2][64*72];       // [t_local][dd]
  __shared__ short Vt[2][64*72];       // [d][t_local]
  __shared__ unsigned Ps[2][4][16*68]; // per-state, per-wave packed P
  const int tid = threadIdx.x, L = tid & 63, w = tid >> 6;
  const int lr = L & 15, lg = L >> 4;
  const int flat = blockIdx.x + (blockIdx.y << 3);       // grid (8,64)
  const int hb = ((flat & 7) << 3) | ((flat >> 3) & 7);  // same hb -> same XCD
  const int sp = flat >> 6;                              // 0..7
  const int h = hb >> 2, b = hb & 3;
  const size_t hbo = (size_t)hb << 16;
  const float NEG_INF = -__builtin_inff();
  int qt[2]; qt[0] = sp; qt[1] = CAUSAL ? (15 - sp) : (sp + 8);

  s8v qfh[2][2], qfl[2][2];
  #pragma unroll
  for (int st = 0; st < 2; st++){
    const size_t qoff = hbo + (size_t)((qt[st] << 6) + (w << 4) + lr) * 64 + (lg << 3);
    qfh[st][0] = *(const s8v*)(qhi + qoff);  qfh[st][1] = *(const s8v*)(qhi + qoff + 32);
    qfl[st][0] = *(const s8v*)(qlo + qoff);  qfl[st][1] = *(const s8v*)(qlo + qoff + 32);
  }

  f4v o[2][4];
  float mprev[2][4], lsum[2][4];
  #pragma unroll
  for (int st = 0; st < 2; st++){
    #pragma unroll
    for (int ni = 0; ni < 4; ni++)
      #pragma unroll
      for (int r = 0; r < 4; r++) o[st][ni][r] = 0.0f;
    #pragma unroll
    for (int r = 0; r < 4; r++){ mprev[st][r] = NEG_INF; lsum[st][r] = 0.0f; }
  }

  const int ntt = CAUSAL ? (qt[1] + 1) : 16;
  for (int ti = 0; ti < ntt; ti++){
    const int t0 = ti << 6;
    const bool actA = !(CAUSAL && ti > qt[0]);
    __syncthreads();
    #pragma unroll
    for (int i = 0; i < 8; i++){
      int c = tid + (i << 8);
      int buf = c >> 9, cc = c & 511, row = cc >> 3, col8 = (cc & 7) << 3;
      const short* g; short* dst;
      if      (buf == 0){ g = khi + hbo + ((size_t)t0 << 6) + ((size_t)cc << 3); dst = &Kt[0][row*72 + col8]; }
      else if (buf == 1){ g = klo + hbo + ((size_t)t0 << 6) + ((size_t)cc << 3); dst = &Kt[1][row*72 + col8]; }
      else if (buf == 2){ g = vhi + hbo + ((size_t)row << 10) + t0 + col8;       dst = &Vt[0][row*72 + col8]; }
      else              { g = vlo + hbo + ((size_t)row << 10) + t0 + col8;       dst = &Vt[1][row*72 + col8]; }
      *(s8v*)dst = *(const s8v*)g;
    }
    __syncthreads();

    // ---- QK for both states; K-frags loaded once
    f4v sa[2][4];
    #pragma unroll
    for (int st = 0; st < 2; st++)
      #pragma unroll
      for (int ni = 0; ni < 4; ni++)
        #pragma unroll
        for (int r = 0; r < 4; r++) sa[st][ni][r] = 0.0f;
    #pragma unroll
    for (int ks = 0; ks < 2; ks++){
      const int kb = (ks << 5) + (lg << 3);
      #pragma unroll
      for (int ni = 0; ni < 4; ni++){
        const int tl = (ni << 4) + lr;
        s8v kbh = *(const s8v*)&Kt[0][tl * 72 + kb];
        s8v kbl = *(const s8v*)&Kt[1][tl * 72 + kb];
        if (actA){
          sa[0][ni] = MFMA(qfh[0][ks], kbh, sa[0][ni], 0, 0, 0);
          sa[0][ni] = MFMA(qfh[0][ks], kbl, sa[0][ni], 0, 0, 0);
          sa[0][ni] = MFMA(qfl[0][ks], kbh, sa[0][ni], 0, 0, 0);
        }
        sa[1][ni] = MFMA(qfh[1][ks], kbh, sa[1][ni], 0, 0, 0);
        sa[1][ni] = MFMA(qfh[1][ks], kbl, sa[1][ni], 0, 0, 0);
        sa[1][ni] = MFMA(qfl[1][ks], kbh, sa[1][ni], 0, 0, 0);
      }
    }

    // ---- softmax + P write per state
    #pragma unroll
    for (int st = 0; st < 2; st++){
      if (st == 0 && !actA) continue;
      const int s0w = (qt[st] << 6) + (w << 4);
      const bool diag = CAUSAL && (ti == qt[st]);
      float tm[4] = {NEG_INF, NEG_INF, NEG_INF, NEG_INF};
      #pragma unroll
      for (int ni = 0; ni < 4; ni++)
        #pragma unroll
        for (int r = 0; r < 4; r++){
          float v = sa[st][ni][r] * 0.125f;
          if (diag){
            int tg = t0 + (ni << 4) + lr;
            int sg = s0w + (lg << 2) + r;
            if (tg > sg) v = NEG_INF;
          }
          sa[st][ni][r] = v;
          tm[r] = fmaxf(tm[r], v);
        }
      #pragma unroll
      for (int off = 1; off < 16; off <<= 1)
        #pragma unroll
        for (int r = 0; r < 4; r++) tm[r] = fmaxf(tm[r], __shfl_xor(tm[r], off, 16));
      float alpha[4], psum[4];
      #pragma unroll
      for (int r = 0; r < 4; r++){
        float mn = fmaxf(mprev[st][r], tm[r]);
        alpha[r] = __expf(mprev[st][r] - mn);
        mprev[st][r] = mn;
        psum[r] = 0.0f;
      }
      #pragma unroll
      for (int ni = 0; ni < 4; ni++)
        #pragma unroll
        for (int r = 0; r < 4; r++){
          float pv = __expf(sa[st][ni][r] - mprev[st][r]);
          sa[st][ni][r] = pv;
          psum[r] += pv;
        }
      #pragma unroll
      for (int off = 1; off < 16; off <<= 1)
        #pragma unroll
        for (int r = 0; r < 4; r++) psum[r] += __shfl_xor(psum[r], off, 16);
      #pragma unroll
      for (int r = 0; r < 4; r++) lsum[st][r] = lsum[st][r] * alpha[r] + psum[r];
      #pragma unroll
      for (int ni = 0; ni < 4; ni++)
        #pragma unroll
        for (int r = 0; r < 4; r++) o[st][ni][r] *= alpha[r];
      #pragma unroll
      for (int ni = 0; ni < 4; ni++)
        #pragma unroll
        for (int r = 0; r < 4; r++){
          int prow = (lg << 2) + r, pcol = (ni << 4) + lr;
          float pv = sa[st][ni][r];
          short hi = f2bf(pv);
          Ps[st][w][prow * 68 + pcol] = pack2(hi, f2bf(pv - bf2f(hi)));
        }
    }

    // ---- PV for both states; V-frags loaded once (same-wave LDS RAW order)
    #pragma unroll
    for (int ks = 0; ks < 2; ks++){
      const int kb = (ks << 5) + (lg << 3);
      s8v ph[2], pl[2];
      #pragma unroll
      for (int st = 0; st < 2; st++){
        if (st == 0 && !actA) continue;
        u4v p0 = *(const u4v*)&Ps[st][w][lr * 68 + kb];
        u4v p1 = *(const u4v*)&Ps[st][w][lr * 68 + kb + 4];
        #pragma unroll
        for (int jj = 0; jj < 4; jj++){
          ph[st][jj]     = (short)(p0[jj] & 0xffffu);  pl[st][jj]     = (short)(p0[jj] >> 16);
          ph[st][4 + jj] = (short)(p1[jj] & 0xffffu);  pl[st][4 + jj] = (short)(p1[jj] >> 16);
        }
      }
      #pragma unroll
      for (int ni = 0; ni < 4; ni++){
        const int d = (ni << 4) + lr;
        s8v vbh = *(const s8v*)&Vt[0][d * 72 + kb];
        s8v vbl = *(const s8v*)&Vt[1][d * 72 + kb];
        if (actA){
          o[0][ni] = MFMA(ph[0], vbh, o[0][ni], 0, 0, 0);
          o[0][ni] = MFMA(ph[0], vbl, o[0][ni], 0, 0, 0);
          o[0][ni] = MFMA(pl[0], vbh, o[0][ni], 0, 0, 0);
        }
        o[1][ni] = MFMA(ph[1], vbh, o[1][ni], 0, 0, 0);
        o[1][ni] = MFMA(ph[1], vbl, o[1][ni], 0, 0, 0);
        o[1][ni] = MFMA(pl[1], vbh, o[1][ni], 0, 0, 0);
      }
    }
  }

  // ---- normalize, scatter to raw head-concat reshape layout (both states)
  #pragma unroll
  for (int st = 0; st < 2; st++){
    const int s0w = (qt[st] << 6) + (w << 4);
    #pragma unroll
    for (int ni = 0; ni < 4; ni++){
      #pragma unroll
      for (int r = 0; r < 4; r++){
        float val = o[st][ni][r] / lsum[st][r];
        int s = s0w + (lg << 2) + r;
        int d = (ni << 4) + lr;
        int s2i = ((h & 3) << 8) | (b << 6) | (s >> 4);
        int c   = ((s & 15) << 6) | d;
        size_t dst = ((size_t)(h >> 2) << 20) + ((size_t)s2i << 10) + c;
        short hi = f2bf(val);
        ohi_g[dst] = hi;
        olo_g[dst] = f2bf(val - bf2f(hi));
      }
    }
  }
}

// ---------------------------------------------------------------------------
// LayerNorm over (S,E) = 1M elems per batch, three-stage.
// ---------------------------------------------------------------------------
__launch_bounds__(256)
__global__ void ln_partial_k(const float* s1, const float* s2, float2* part){
  const int tid = threadIdx.x, L = tid & 63, w = tid >> 6;
  const int b = blockIdx.y, j = blockIdx.x;
  const size_t base = ((size_t)b << 20) + ((size_t)j << 13) + ((size_t)tid << 2);
  float sum = 0.0f, ss = 0.0f;
  #pragma unroll
  for (int i = 0; i < 8; i++){
    size_t idx = base + ((size_t)i << 10);
    float4 v = *(const float4*)(s1 + idx);
    if (s2){
      float4 u = *(const float4*)(s2 + idx);
      v.x += u.x; v.y += u.y; v.z += u.z; v.w += u.w;
    }
    sum += v.x + v.y + v.z + v.w;
    ss  += v.x*v.x + v.y*v.y + v.z*v.z + v.w*v.w;
  }
  #pragma unroll
  for (int off = 1; off < 64; off <<= 1){
    sum += __shfl_xor(sum, off, 64);
    ss  += __shfl_xor(ss,  off, 64);
  }
  __shared__ float red[4][2];
  if (L == 0){ red[w][0] = sum; red[w][1] = ss; }
  __syncthreads();
  if (tid == 0){
    float s_ = red[0][0] + red[1][0] + red[2][0] + red[3][0];
    float q_ = red[0][1] + red[1][1] + red[2][1] + red[3][1];
    part[b * 128 + j] = make_float2(s_, q_);
  }
}

__launch_bounds__(64)
__global__ void ln_final_k(const float2* part, float2* stats){
  const int b = blockIdx.x, t = threadIdx.x;
  float2 a = part[b * 128 + t], c = part[b * 128 + 64 + t];
  float sum = a.x + c.x, ss = a.y + c.y;
  #pragma unroll
  for (int off = 1; off < 64; off <<= 1){
    sum += __shfl_xor(sum, off, 64);
    ss  += __shfl_xor(ss,  off, 64);
  }
  if (t == 0){
    float mean = sum * (1.0f / 1048576.0f);
    float var  = ss  * (1.0f / 1048576.0f) - mean * mean;
    stats[b] = make_float2(mean, rsqrtf(var + 1e-5f));
  }
}

// MODE 0: hi/lo planes | MODE 1: fp32 + hi/lo planes | MODE 2: fp32 out only
template<int MODE>
__launch_bounds__(256)
__global__ void ln_apply_k(const float* s1, const float* s2,
                           const float* wgt, const float* bias,
                           const float2* stats,
                           float* dstf, short* dsta, short* dstb){
  const int tid = threadIdx.x;
  const size_t base = ((size_t)blockIdx.x << 11) + ((size_t)tid << 2);
  #pragma unroll
  for (int i = 0; i < 2; i++){
    size_t idx = base + ((size_t)i << 10);
    int b = (int)(idx >> 20);
    float2 st = stats[b];
    float4 x = *(const float4*)(s1 + idx);
    if (s2){
      float4 u = *(const float4*)(s2 + idx);
      x.x += u.x; x.y += u.y; x.z += u.z; x.w += u.w;
    }
    unsigned wi = (unsigned)(idx & 1048575u);
    float4 wv = *(const float4*)(wgt + wi);
    float4 bv = *(const float4*)(bias + wi);
    float xv[4] = {x.x, x.y, x.z, x.w};
    float wvv[4] = {wv.x, wv.y, wv.z, wv.w};
    float bvv[4] = {bv.x, bv.y, bv.z, bv.w};
    float yv[4];
    #pragma unroll
    for (int c = 0; c < 4; c++)
      yv[c] = (xv[c] - st.x) * st.y * wvv[c] + bvv[c];
    if (MODE == 0 || MODE == 1){
      short h[4], l[4];
      #pragma unroll
      for (int c = 0; c < 4; c++){
        h[c] = f2bf(yv[c]);
        l[c] = f2bf(yv[c] - bf2f(h[c]));
      }
      *(short4*)(dsta + idx) = make_short4(h[0], h[1], h[2], h[3]);
      *(short4*)(dstb + idx) = make_short4(l[0], l[1], l[2], l[3]);
      if (MODE == 1)
        *(float4*)(dstf + idx) = make_float4(yv[0], yv[1], yv[2], yv[3]);
    } else {
      *(float4*)(dstf + idx) = make_float4(yv[0], yv[1], yv[2], yv[3]);
    }
  }
}

// ---------------------------------------------------------------------------
extern "C" void kernel_launch(void* const* d_in, const int* in_sizes, int n_in,
                              void* d_out, int out_size, void* d_ws, size_t ws_size,
                              hipStream_t stream){
  const float* IRf = (const float*)d_in[0];
  const float* OEf = (const float*)d_in[1];
  const float* Wq1f = (const float*)d_in[2];
  const float* Wk1f = (const float*)d_in[3];
  const float* Wv1f = (const float*)d_in[4];
  const float* Wo1f = (const float*)d_in[5];
  const float* Wq2f = (const float*)d_in[6];
  const float* Wk2f = (const float*)d_in[7];
  const float* Wv2f = (const float*)d_in[8];
  const float* Wo2f = (const float*)d_in[9];
  const float* ln1w = (const float*)d_in[10];
  const float* ln1b = (const float*)d_in[11];
  const float* ln2w = (const float*)d_in[12];
  const float* ln2b = (const float*)d_in[13];
  const float* ln3w = (const float*)d_in[14];
  const float* ln3b = (const float*)d_in[15];
  const float* W1f = (const float*)d_in[16];
  const float* b1f = (const float*)d_in[17];
  const float* W2f = (const float*)d_in[18];
  const float* b2f = (const float*)d_in[19];
  float* dout = (float*)d_out;

  char* ws = (char*)d_ws;
  const size_t MB = (size_t)1 << 20;
  short* OEh = (short*)(ws + 0*MB),  *OEl = (short*)(ws + 8*MB);
  short* IRh = (short*)(ws + 16*MB), *IRl = (short*)(ws + 24*MB);
  short* QKV1t_h = (short*)(ws + 32*MB), *QKV1t_l = (short*)(ws + 38*MB);  // [3072][1024]
  short* Wo1t_h  = (short*)(ws + 44*MB), *Wo1t_l  = (short*)(ws + 46*MB);  // [1024][1024]
  short* Q2t_h   = (short*)(ws + 48*MB), *Q2t_l   = (short*)(ws + 50*MB);
  short* KV2t_h  = (short*)(ws + 52*MB), *KV2t_l  = (short*)(ws + 56*MB);  // [2048][1024]
  short* Wo2t_h  = (short*)(ws + 60*MB), *Wo2t_l  = (short*)(ws + 62*MB);
  short* W1t_h   = (short*)(ws + 64*MB), *W1t_l   = (short*)(ws + 68*MB);  // [2048][1024]
  short* W2t_h   = (short*)(ws + 72*MB), *W2t_l   = (short*)(ws + 76*MB);  // [1024][2048]
  short* q_h = (short*)(ws + 80*MB),  *q_l = (short*)(ws + 88*MB);
  short* k_h = (short*)(ws + 96*MB),  *k_l = (short*)(ws + 104*MB);
  short* v_h = (short*)(ws + 112*MB), *v_l = (short*)(ws + 120*MB);
  short* outr_h = (short*)(ws + 128*MB), *outr_l = (short*)(ws + 136*MB);
  float* resid = (float*)(ws + 144*MB);
  short* attn_h = (short*)(ws + 160*MB), *attn_l = (short*)(ws + 168*MB);
  float* att2n_f = (float*)(ws + 176*MB);
  // aliases (dead ranges)
  short* hid_h = (short*)(ws + 80*MB);   // [4096][2048] over q planes
  short* hid_l = (short*)(ws + 96*MB);   // over k planes
  float* fc    = (float*)(ws + 112*MB);  // over v planes
  short* a2n_h = (short*)(ws + 160*MB);  // over attn planes
  short* a2n_l = (short*)(ws + 168*MB);
  float2* part  = (float2*)(ws + 192*MB);
  float2* stats = (float2*)(ws + 192*MB + 65536);

  dim3 blk(256);

  // ---- split OE/IR into bf16 hi/lo planes
  SplitP sp;
  sp.src[0] = OEf; sp.hi[0] = OEh; sp.lo[0] = OEl;
  sp.src[1] = IRf; sp.hi[1] = IRh; sp.lo[1] = IRl;
  splitall_k<<<dim3(4096, 2), blk, 0, stream>>>(sp);

  // ---- batched weight transpose to [N][K] hi/lo planes
  TransP tp;
  const float* tsrc[10] = {Wq1f, Wk1f, Wv1f, Wo1f, Wq2f, Wk2f, Wv2f, Wo2f, W1f, W2f};
  short* toh[10] = {QKV1t_h, QKV1t_h + (1<<20), QKV1t_h + (2<<20), Wo1t_h,
                    Q2t_h, KV2t_h, KV2t_h + (1<<20), Wo2t_h, W1t_h, W2t_h};
  short* tol[10] = {QKV1t_l, QKV1t_l + (1<<20), QKV1t_l + (2<<20), Wo1t_l,
                    Q2t_l, KV2t_l, KV2t_l + (1<<20), Wo2t_l, W1t_l, W2t_l};
  int tK[10]   = {1024,1024,1024,1024,1024,1024,1024,1024,1024,2048};
  int tN[10]   = {1024,1024,1024,1024,1024,1024,1024,1024,2048,1024};
  int tq[10]   = {1,1,1,0,1,1,1,0,0,0};
  int tt[10]   = {256,256,256,256,256,256,256,256,512,512};
  for (int i = 0; i < 10; i++){
    tp.src[i] = tsrc[i]; tp.oh[i] = toh[i]; tp.ol[i] = tol[i];
    tp.Kd[i] = tK[i]; tp.Nd[i] = tN[i]; tp.qkv[i] = tq[i]; tp.ntiles[i] = tt[i];
  }
  transall_k<<<dim3(512, 10), blk, 0, stream>>>(tp);

  GemmP p{};

  // ===== MHA1 (self, causal) =====
  p = {OEh, OEl, 1024, QKV1t_h, QKV1t_l, 1024, 1024, 3072, nullptr, nullptr,
       nullptr, q_h, q_l, k_h, k_l, v_h, v_l};
  gemm_k<6,3><<<dim3(24, 32), blk, 0, stream>>>(p);
  flash_k<1><<<dim3(8, 64), blk, 0, stream>>>(q_h, q_l, k_h, k_l, v_h, v_l, outr_h, outr_l);
  p = {outr_h, outr_l, 1024, Wo1t_h, Wo1t_l, 1024, 1024, 1024, OEf, nullptr,
       resid, nullptr, nullptr, nullptr, nullptr, nullptr, nullptr};
  gemm_k<2,3><<<dim3(8, 32), blk, 0, stream>>>(p);
  ln_partial_k<<<dim3(128, 4), blk, 0, stream>>>(resid, nullptr, part);
  ln_final_k<<<dim3(4), dim3(64), 0, stream>>>(part, stats);
  ln_apply_k<0><<<dim3(2048), blk, 0, stream>>>(resid, nullptr, ln1w, ln1b, stats, nullptr, attn_h, attn_l);

  // ===== MHA2 (cross: KV from inputRes, Q from att_norm, no mask) =====
  p = {attn_h, attn_l, 1024, Q2t_h, Q2t_l, 1024, 1024, 1024, nullptr, nullptr,
       nullptr, q_h, q_l, nullptr, nullptr, nullptr, nullptr};
  gemm_k<0,3><<<dim3(8, 32), blk, 0, stream>>>(p);
  p = {IRh, IRl, 1024, KV2t_h, KV2t_l, 1024, 1024, 2048, nullptr, nullptr,
       nullptr, k_h, k_l, v_h, v_l, nullptr, nullptr};
  gemm_k<7,3><<<dim3(16, 32), blk, 0, stream>>>(p);
  flash_k<0><<<dim3(8, 64), blk, 0, stream>>>(q_h, q_l, k_h, k_l, v_h, v_l, outr_h, outr_l);
  p = {outr_h, outr_l, 1024, Wo2t_h, Wo2t_l, 1024, 1024, 1024, OEf, nullptr,
       resid, nullptr, nullptr, nullptr, nullptr, nullptr, nullptr};
  gemm_k<2,3><<<dim3(8, 32), blk, 0, stream>>>(p);
  ln_partial_k<<<dim3(128, 4), blk, 0, stream>>>(resid, nullptr, part);
  ln_final_k<<<dim3(4), dim3(64), 0, stream>>>(part, stats);
  ln_apply_k<1><<<dim3(2048), blk, 0, stream>>>(resid, nullptr, ln2w, ln2b, stats, att2n_f, a2n_h, a2n_l);

  // ===== FFN ((B,S,E)->(B,E,S) raw reshape is a flat no-op); 2-term =====
  p = {a2n_h, a2n_l, 1024, W1t_h, W1t_l, 1024, 1024, 2048, nullptr, b1f,
       nullptr, hid_h, hid_l, nullptr, nullptr, nullptr, nullptr};
  gemm_k<3,2><<<dim3(16, 32), blk, 0, stream>>>(p);
  p = {hid_h, hid_l, 2048, W2t_h, W2t_l, 2048, 2048, 1024, nullptr, b2f,
       fc, nullptr, nullptr, nullptr, nullptr, nullptr, nullptr};
  gemm_k<4,2><<<dim3(8, 32), blk, 0, stream>>>(p);
  ln_partial_k<<<dim3(128, 4), blk, 0, stream>>>(fc, att2n_f, part);
  ln_final_k<<<dim3(4), dim3(64), 0, stream>>>(part, stats);
  ln_apply_k<2><<<dim3(2048), blk, 0, stream>>>(fc, att2n_f, ln3w, ln3b, stats, dout, nullptr, nullptr);
}

// Round 6
// 735.044 us; speedup vs baseline: 1.7875x; 1.1850x over previous
//
#include <hip/hip_runtime.h>
#include <cstdint>
#include <cstddef>

// ============================================================================
// transformer_11441792877290 — MI355X fp32, round 6
// B=4 S=1024 E=1024 H=16 DK=64 FF=2048, SCALE=8, EPS=1e-5
// vs round 5 (passed, 871us, absmax 0.1016):
//  * GEMM: 512-thr blocks, ring-3 LDS, prefetch distance 2, raw
//    asm s_waitcnt vmcnt(N)+s_barrier (never vmcnt(0) in steady state).
//    TM=256 tile for N>=2048, TM=128 for N=1024 grids.
//  * q/K2^T/V^T packed u32 (hi|lo): halves scatter stores, kills the 8x
//    K2^T line false-sharing (220MB -> ~70MB writes on QKV1).
// ============================================================================

#define DI __device__ __forceinline__
#define MFMA __builtin_amdgcn_mfma_f32_16x16x32_bf16

typedef short s8v __attribute__((ext_vector_type(8)));
typedef float f4v __attribute__((ext_vector_type(4)));
typedef unsigned u4v __attribute__((ext_vector_type(4)));

DI float bf2f(short u){
  union { unsigned int i; float f; } v;
  v.i = ((unsigned int)(unsigned short)u) << 16;
  return v.f;
}
DI short f2bf(float f){  // round-to-nearest-even
  union { float f; unsigned int i; } v; v.f = f;
  unsigned int x = v.i;
  return (short)((x + 0x7fffu + ((x >> 16) & 1u)) >> 16);
}
DI unsigned pack2(short hi, short lo){
  return ((unsigned)(unsigned short)lo << 16) | (unsigned)(unsigned short)hi;
}
DI unsigned packf(float val){
  short hi = f2bf(val);
  return pack2(hi, f2bf(val - bf2f(hi)));
}
DI void gload16(const void* g, void* l){
  __builtin_amdgcn_global_load_lds(
      (const __attribute__((address_space(1))) unsigned*)g,
      (__attribute__((address_space(3))) unsigned*)l, 16, 0, 0);
}

// ---------------------------------------------------------------------------
// fp32 -> bf16 hi/lo plane split (OE, IR)
// ---------------------------------------------------------------------------
struct SplitP { const float* src[2]; short* hi[2]; short* lo[2]; };

__launch_bounds__(256)
__global__ void splitall_k(SplitP sp){
  const int t = blockIdx.y;
  int i = (blockIdx.x * 256 + threadIdx.x) << 2;
  float4 v = *(const float4*)(sp.src[t] + i);
  float xs[4] = {v.x, v.y, v.z, v.w};
  short h[4], l[4];
  #pragma unroll
  for (int c = 0; c < 4; c++){
    h[c] = f2bf(xs[c]);
    l[c] = f2bf(xs[c] - bf2f(h[c]));
  }
  *(short4*)(sp.hi[t] + i) = make_short4(h[0], h[1], h[2], h[3]);
  *(short4*)(sp.lo[t] + i) = make_short4(l[0], l[1], l[2], l[3]);
}

// ---------------------------------------------------------------------------
// Batched weight transpose: fp32 [K][N] (or [H][E][DK] qkv gather) ->
// bf16 hi/lo planes [N][K]. 64x64 tiles via LDS.
// ---------------------------------------------------------------------------
struct TransP {
  const float* src[10];
  short* oh[10]; short* ol[10];
  int Kd[10]; int Nd[10]; int qkv[10]; int ntiles[10];
};

__launch_bounds__(256)
__global__ void transall_k(TransP tp){
  const int t = blockIdx.y;
  const int tile = blockIdx.x;
  if (tile >= tp.ntiles[t]) return;
  const int K = tp.Kd[t], N = tp.Nd[t];
  const int ncols = N >> 6;
  const int n0 = (tile % ncols) << 6, k0 = (tile / ncols) << 6;
  __shared__ float Ld[64 * 65];
  const int tid = threadIdx.x;
  const int row = tid >> 2, c16 = (tid & 3) << 4;
  const float* s = tp.src[t];
  size_t base;
  if (tp.qkv[t]) base = ((size_t)(n0 >> 6) << 16) + ((size_t)(k0 + row) << 6) + c16;
  else           base = (size_t)(k0 + row) * N + n0 + c16;
  #pragma unroll
  for (int j4 = 0; j4 < 4; j4++){
    float4 v = *(const float4*)(s + base + (j4 << 2));
    int c = row * 65 + c16 + (j4 << 2);
    Ld[c] = v.x; Ld[c + 1] = v.y; Ld[c + 2] = v.z; Ld[c + 3] = v.w;
  }
  __syncthreads();
  const int n = tid >> 2;
  s8v h0, h1, l0, l1;
  #pragma unroll
  for (int j = 0; j < 8; j++){
    float a = Ld[(c16 + j) * 65 + n];
    float b = Ld[(c16 + 8 + j) * 65 + n];
    short ha = f2bf(a), hb = f2bf(b);
    h0[j] = ha; l0[j] = f2bf(a - bf2f(ha));
    h1[j] = hb; l1[j] = f2bf(b - bf2f(hb));
  }
  size_t ob = (size_t)(n0 + n) * K + k0 + c16;
  *(s8v*)(tp.oh[t] + ob)     = h0;
  *(s8v*)(tp.oh[t] + ob + 8) = h1;
  *(s8v*)(tp.ol[t] + ob)     = l0;
  *(s8v*)(tp.ol[t] + ob + 8) = l1;
}

// ---------------------------------------------------------------------------
// Split-bf16 GEMM, pipelined: C[M,N] = (Ah+Al)[M,K] x (Bh+Bl)[K,N], B=B^T[N][K]
// 512 thr = 8 waves; tile TM x 128, BK=32; ring-3 LDS, prefetch distance 2,
// raw s_waitcnt vmcnt(NG)+s_barrier per iter. TERMS 3: hh+hl+lh; 2: hh+hl.
// EPI 0: packed q scatter              2: fp32 = acc + xres
//     3: hi/lo planes = relu(acc+bias) 4: fp32 = acc + bias
//     6: QKV packed (q / K2^T / V^T)   7: KV packed (K2^T / V^T)
// ---------------------------------------------------------------------------
struct GemmP {
  const short* Ah; const short* Al; int lda;
  const short* Bh; const short* Bl; int ldb;
  int K; int N;
  const float* xres; const float* bias;
  float* outf;
  short* o1h; short* o1l;
  unsigned* p1; unsigned* p2; unsigned* p3;
};

template<int TM, int EPI, int TERMS>
__launch_bounds__(512, 2)
__global__ void gemm_k(GemmP p){
  constexpr int NG = TM / 64 + 2;          // gll per wave per tile (6 or 4)
  constexpr int WM = TM >> 6;              // waves along m (4 or 2)
  constexpr int NB = 128 / (8 / WM) / 16;  // n-frags per wave (4 or 2)
  __shared__ short AhL[3][TM * 32];
  __shared__ short AlL[3][TM * 32];
  __shared__ short BhL[3][128 * 32];
  __shared__ short BlL[3][128 * 32];
  const int tid = threadIdx.x;
  const int L = tid & 63, w = tid >> 6;
  const int lr = L & 15, lg = L >> 4;
  const int mo = (w & (WM - 1)) << 6;
  const int no = (w / WM) * (NB << 4);

  // ---- XCD swizzle: flat%8 = xcd; within xcd, n varies fastest
  const int gx = gridDim.x, gy = gridDim.y;
  const int f = blockIdx.y * gx + blockIdx.x;
  const int j = f >> 3;
  const int jm = j / gx;
  const int mb = (f & 7) * (gy >> 3) + jm;
  const int nb = j - jm * gx;
  const int m0 = mb * TM, n0 = nb << 7;

  const int lrow4 = L >> 2, lcol8 = (L & 3) << 3;

  f4v acc[4][NB];
  #pragma unroll
  for (int i = 0; i < 4; i++)
    #pragma unroll
    for (int jj = 0; jj < NB; jj++)
      #pragma unroll
      for (int r = 0; r < 4; r++) acc[i][jj][r] = 0.0f;

  const int nkt = p.K >> 5;

  // stage tile t into ring slot
  auto stage = [&](int tile, int slot){
    const int k0 = tile << 5;
    #pragma unroll
    for (int i = 0; i < NG; i++){
      int base_c = (i << 9) + (w << 6);    // wave-uniform
      const short* g; short* lp;
      if (base_c < TM * 4){
        int pc = base_c;
        g = p.Ah + (size_t)(m0 + (pc >> 2) + lrow4) * p.lda + k0 + lcol8;
        lp = &AhL[slot][pc << 3];
      } else if (base_c < TM * 8){
        int pc = base_c - TM * 4;
        g = p.Al + (size_t)(m0 + (pc >> 2) + lrow4) * p.lda + k0 + lcol8;
        lp = &AlL[slot][pc << 3];
      } else if (base_c < TM * 8 + 512){
        int pc = base_c - TM * 8;
        g = p.Bh + (size_t)(n0 + (pc >> 2) + lrow4) * p.ldb + k0 + lcol8;
        lp = &BhL[slot][pc << 3];
      } else {
        int pc = base_c - TM * 8 - 512;
        g = p.Bl + (size_t)(n0 + (pc >> 2) + lrow4) * p.ldb + k0 + lcol8;
        lp = &BlL[slot][pc << 3];
      }
      gload16(g, lp);
    }
  };

  // prologue: tiles 0,1 -> slots 0,1
  stage(0, 0);
  stage(1, 1);

  for (int kt = 0; kt < nkt; kt++){
    const int cur = kt % 3;
    // wait until only the kt+1 prefetch (NG gll) remains in flight, then sync
    asm volatile("s_waitcnt vmcnt(%0)\n\ts_barrier" :: "i"(NG) : "memory");

    const int kbd = lg << 3;
    s8v a_h[4], a_l[4], b_h[NB], b_l[NB];
    #pragma unroll
    for (int mi = 0; mi < 4; mi++){
      const int row = mo + (mi << 4) + lr;
      a_h[mi] = *(const s8v*)&AhL[cur][(row << 5) + kbd];
      a_l[mi] = *(const s8v*)&AlL[cur][(row << 5) + kbd];
    }
    #pragma unroll
    for (int ni = 0; ni < NB; ni++){
      const int n = no + (ni << 4) + lr;
      b_h[ni] = *(const s8v*)&BhL[cur][(n << 5) + kbd];
      b_l[ni] = *(const s8v*)&BlL[cur][(n << 5) + kbd];
    }

    // issue distance-2 prefetch (clamped at the end to keep vmcnt cadence;
    // re-staging the last tile into a dead slot is idempotent/harmless)
    int nt = kt + 2 < nkt ? kt + 2 : nkt - 1;
    stage(nt, (kt + 2) % 3);

    #pragma unroll
    for (int ni = 0; ni < NB; ni++){
      #pragma unroll
      for (int mi = 0; mi < 4; mi++){
        acc[mi][ni] = MFMA(a_h[mi], b_h[ni], acc[mi][ni], 0, 0, 0);
        acc[mi][ni] = MFMA(a_h[mi], b_l[ni], acc[mi][ni], 0, 0, 0);
        if (TERMS == 3)
          acc[mi][ni] = MFMA(a_l[mi], b_h[ni], acc[mi][ni], 0, 0, 0);
      }
    }
  }

  // ---- epilogue (C/D map: col = lane&15, row = (lane>>4)*4 + reg)
  #pragma unroll
  for (int mi = 0; mi < 4; mi++){
    #pragma unroll
    for (int ni = 0; ni < NB; ni++){
      #pragma unroll
      for (int r = 0; r < 4; r++){
        float val = acc[mi][ni][r];
        int m = m0 + mo + (mi << 4) + (lg << 2) + r;
        int n = n0 + no + (ni << 4) + lr;
        if (EPI == 2){
          size_t o = (size_t)m * p.N + n;
          p.outf[o] = val + p.xres[o];
        } else if (EPI == 4){
          p.outf[(size_t)m * p.N + n] = val + p.bias[n];
        } else if (EPI == 3){
          float x = val + p.bias[n];
          x = x > 0.0f ? x : 0.0f;
          size_t o = (size_t)m * p.N + n;
          short hi = f2bf(x);
          p.o1h[o] = hi;
          p.o1l[o] = f2bf(x - bf2f(hi));
        } else {
          // packed scatter: EPI 0 (q), 6 (q/K2^T/V^T), 7 (K2^T/V^T)
          int seg = (EPI == 0) ? 0 : (n >> 10);
          int n1 = (EPI == 0) ? n : (n & 1023);
          int kind = (EPI == 0) ? 0 : (EPI == 6 ? seg : seg + 1);
          int b = m >> 10, s = m & 1023, hh = n1 >> 6, d = n1 & 63;
          size_t hb16 = (size_t)((hh << 2) | b) << 16;
          size_t dst;
          if (kind == 0)      dst = hb16 + ((size_t)s << 6) + d;
          else if (kind == 1) dst = hb16 + ((size_t)(((s & 15) << 6) | d) << 6) + (s >> 4);
          else                dst = hb16 + ((size_t)d << 10) + s;
          unsigned* dp = (EPI == 0) ? p.p1
                       : (EPI == 6) ? (seg == 0 ? p.p1 : (seg == 1 ? p.p2 : p.p3))
                                    : (seg == 0 ? p.p1 : p.p2);
          dp[dst] = packf(val);
        }
      }
    }
  }
}

// ---------------------------------------------------------------------------
// Flash attention, paired Q-tiles, packed u32 q/K2^T/V^T inputs.
// Per (h,b): Q[1024,64] x K2[64,1024] -> softmax/8 -> x V.
// K packed as K2^T[hb][t][dd], V as V^T[hb][d][s], q as [hb][s][d].
// Block owns Q-tiles (sp, 15-sp) [causal] or (sp, sp+8) [cross].
// ---------------------------------------------------------------------------
template<int CAUSAL>
__launch_bounds__(256, 2)
__global__ void flash_k(const unsigned* __restrict__ qpk,
                        const unsigned* __restrict__ kpk,
                        const unsigned* __restrict__ vpk,
                        short* __restrict__ ohi_g, short* __restrict__ olo_g){
  __shared__ short Kt[2][64*72];       // [t_local][dd] hi/lo
  __shared__ short Vt[2][64*72];       // [d][t_local] hi/lo
  __shared__ unsigned Ps[2][4][16*68]; // per-state, per-wave packed P
  const int tid = threadIdx.x, L = tid & 63, w = tid >> 6;
  const int lr = L & 15, lg = L >> 4;
  const int flat = blockIdx.x + (blockIdx.y << 3);       // grid (8,64)
  const int hb = ((flat & 7) << 3) | ((flat >> 3) & 7);  // same hb -> same XCD
  const int sp = flat >> 6;                              // 0..7
  const int h = hb >> 2, b = hb & 3;
  const size_t hbo = (size_t)hb << 16;
  const float NEG_INF = -__builtin_inff();
  int qt[2]; qt[0] = sp; qt[1] = CAUSAL ? (15 - sp) : (sp + 8);

  s8v qfh[2][2], qfl[2][2];
  #pragma unroll
  for (int st = 0; st < 2; st++){
    const unsigned* qg = qpk + hbo + (size_t)((qt[st] << 6) + (w << 4) + lr) * 64 + (lg << 3);
    #pragma unroll
    for (int ks = 0; ks < 2; ks++){
      u4v p0 = *(const u4v*)(qg + (ks << 5));
      u4v p1 = *(const u4v*)(qg + (ks << 5) + 4);
      #pragma unroll
      for (int jj = 0; jj < 4; jj++){
        qfh[st][ks][jj]     = (short)(p0[jj] & 0xffffu);
        qfl[st][ks][jj]     = (short)(p0[jj] >> 16);
        qfh[st][ks][4 + jj] = (short)(p1[jj] & 0xffffu);
        qfl[st][ks][4 + jj] = (short)(p1[jj] >> 16);
      }
    }
  }

  f4v o[2][4];
  float mprev[2][4], lsum[2][4];
  #pragma unroll
  for (int st = 0; st < 2; st++){
    #pragma unroll
    for (int ni = 0; ni < 4; ni++)
      #pragma unroll
      for (int r = 0; r < 4; r++) o[st][ni][r] = 0.0f;
    #pragma unroll
    for (int r = 0; r < 4; r++){ mprev[st][r] = NEG_INF; lsum[st][r] = 0.0f; }
  }

  const int ntt = CAUSAL ? (qt[1] + 1) : 16;
  for (int ti = 0; ti < ntt; ti++){
    const int t0 = ti << 6;
    const bool actA = !(CAUSAL && ti > qt[0]);
    __syncthreads();
    {
      // stage K tile [tl][dd] and V tile [d][tl]: packed loads, unpack, b128 LDS
      const int row = tid >> 2, col = (tid & 3) << 4;
      const unsigned* kg = kpk + hbo + (size_t)(t0 + row) * 64 + col;
      const unsigned* vg = vpk + hbo + ((size_t)row << 10) + t0 + col;
      unsigned kb[16], vb[16];
      #pragma unroll
      for (int j4 = 0; j4 < 4; j4++){
        *(u4v*)&kb[j4 << 2] = *(const u4v*)(kg + (j4 << 2));
        *(u4v*)&vb[j4 << 2] = *(const u4v*)(vg + (j4 << 2));
      }
      s8v kh0, kh1, kl0, kl1, vh0, vh1, vl0, vl1;
      #pragma unroll
      for (int jj = 0; jj < 8; jj++){
        kh0[jj] = (short)(kb[jj] & 0xffffu);      kl0[jj] = (short)(kb[jj] >> 16);
        kh1[jj] = (short)(kb[8 + jj] & 0xffffu);  kl1[jj] = (short)(kb[8 + jj] >> 16);
        vh0[jj] = (short)(vb[jj] & 0xffffu);      vl0[jj] = (short)(vb[jj] >> 16);
        vh1[jj] = (short)(vb[8 + jj] & 0xffffu);  vl1[jj] = (short)(vb[8 + jj] >> 16);
      }
      const int lb = row * 72 + col;
      *(s8v*)&Kt[0][lb] = kh0;  *(s8v*)&Kt[0][lb + 8] = kh1;
      *(s8v*)&Kt[1][lb] = kl0;  *(s8v*)&Kt[1][lb + 8] = kl1;
      *(s8v*)&Vt[0][lb] = vh0;  *(s8v*)&Vt[0][lb + 8] = vh1;
      *(s8v*)&Vt[1][lb] = vl0;  *(s8v*)&Vt[1][lb + 8] = vl1;
    }
    __syncthreads();

    // ---- QK for both states; K-frags loaded once
    f4v sa[2][4];
    #pragma unroll
    for (int st = 0; st < 2; st++)
      #pragma unroll
      for (int ni = 0; ni < 4; ni++)
        #pragma unroll
        for (int r = 0; r < 4; r++) sa[st][ni][r] = 0.0f;
    #pragma unroll
    for (int ks = 0; ks < 2; ks++){
      const int kb = (ks << 5) + (lg << 3);
      #pragma unroll
      for (int ni = 0; ni < 4; ni++){
        const int tl = (ni << 4) + lr;
        s8v kbh = *(const s8v*)&Kt[0][tl * 72 + kb];
        s8v kbl = *(const s8v*)&Kt[1][tl * 72 + kb];
        if (actA){
          sa[0][ni] = MFMA(qfh[0][ks], kbh, sa[0][ni], 0, 0, 0);
          sa[0][ni] = MFMA(qfh[0][ks], kbl, sa[0][ni], 0, 0, 0);
          sa[0][ni] = MFMA(qfl[0][ks], kbh, sa[0][ni], 0, 0, 0);
        }
        sa[1][ni] = MFMA(qfh[1][ks], kbh, sa[1][ni], 0, 0, 0);
        sa[1][ni] = MFMA(qfh[1][ks], kbl, sa[1][ni], 0, 0, 0);
        sa[1][ni] = MFMA(qfl[1][ks], kbh, sa[1][ni], 0, 0, 0);
      }
    }

    // ---- softmax + P write per state
    #pragma unroll
    for (int st = 0; st < 2; st++){
      if (st == 0 && !actA) continue;
      const int s0w = (qt[st] << 6) + (w << 4);
      const bool diag = CAUSAL && (ti == qt[st]);
      float tm[4] = {NEG_INF, NEG_INF, NEG_INF, NEG_INF};
      #pragma unroll
      for (int ni = 0; ni < 4; ni++)
        #pragma unroll
        for (int r = 0; r < 4; r++){
          float v = sa[st][ni][r] * 0.125f;
          if (diag){
            int tg = t0 + (ni << 4) + lr;
            int sg = s0w + (lg << 2) + r;
            if (tg > sg) v = NEG_INF;
          }
          sa[st][ni][r] = v;
          tm[r] = fmaxf(tm[r], v);
        }
      #pragma unroll
      for (int off = 1; off < 16; off <<= 1)
        #pragma unroll
        for (int r = 0; r < 4; r++) tm[r] = fmaxf(tm[r], __shfl_xor(tm[r], off, 16));
      float alpha[4], psum[4];
      #pragma unroll
      for (int r = 0; r < 4; r++){
        float mn = fmaxf(mprev[st][r], tm[r]);
        alpha[r] = __expf(mprev[st][r] - mn);
        mprev[st][r] = mn;
        psum[r] = 0.0f;
      }
      #pragma unroll
      for (int ni = 0; ni < 4; ni++)
        #pragma unroll
        for (int r = 0; r < 4; r++){
          float pv = __expf(sa[st][ni][r] - mprev[st][r]);
          sa[st][ni][r] = pv;
          psum[r] += pv;
        }
      #pragma unroll
      for (int off = 1; off < 16; off <<= 1)
        #pragma unroll
        for (int r = 0; r < 4; r++) psum[r] += __shfl_xor(psum[r], off, 16);
      #pragma unroll
      for (int r = 0; r < 4; r++) lsum[st][r] = lsum[st][r] * alpha[r] + psum[r];
      #pragma unroll
      for (int ni = 0; ni < 4; ni++)
        #pragma unroll
        for (int r = 0; r < 4; r++) o[st][ni][r] *= alpha[r];
      #pragma unroll
      for (int ni = 0; ni < 4; ni++)
        #pragma unroll
        for (int r = 0; r < 4; r++){
          int prow = (lg << 2) + r, pcol = (ni << 4) + lr;
          Ps[st][w][prow * 68 + pcol] = packf(sa[st][ni][r]);
        }
    }

    // ---- PV for both states; V-frags loaded once (same-wave LDS RAW order)
    #pragma unroll
    for (int ks = 0; ks < 2; ks++){
      const int kb = (ks << 5) + (lg << 3);
      s8v ph[2], pl[2];
      #pragma unroll
      for (int st = 0; st < 2; st++){
        if (st == 0 && !actA) continue;
        u4v p0 = *(const u4v*)&Ps[st][w][lr * 68 + kb];
        u4v p1 = *(const u4v*)&Ps[st][w][lr * 68 + kb + 4];
        #pragma unroll
        for (int jj = 0; jj < 4; jj++){
          ph[st][jj]     = (short)(p0[jj] & 0xffffu);  pl[st][jj]     = (short)(p0[jj] >> 16);
          ph[st][4 + jj] = (short)(p1[jj] & 0xffffu);  pl[st][4 + jj] = (short)(p1[jj] >> 16);
        }
      }
      #pragma unroll
      for (int ni = 0; ni < 4; ni++){
        const int d = (ni << 4) + lr;
        s8v vbh = *(const s8v*)&Vt[0][d * 72 + kb];
        s8v vbl = *(const s8v*)&Vt[1][d * 72 + kb];
        if (actA){
          o[0][ni] = MFMA(ph[0], vbh, o[0][ni], 0, 0, 0);
          o[0][ni] = MFMA(ph[0], vbl, o[0][ni], 0, 0, 0);
          o[0][ni] = MFMA(pl[0], vbh, o[0][ni], 0, 0, 0);
        }
        o[1][ni] = MFMA(ph[1], vbh, o[1][ni], 0, 0, 0);
        o[1][ni] = MFMA(ph[1], vbl, o[1][ni], 0, 0, 0);
        o[1][ni] = MFMA(pl[1], vbh, o[1][ni], 0, 0, 0);
      }
    }
  }

  // ---- normalize, scatter to raw head-concat reshape layout (both states)
  #pragma unroll
  for (int st = 0; st < 2; st++){
    const int s0w = (qt[st] << 6) + (w << 4);
    #pragma unroll
    for (int ni = 0; ni < 4; ni++){
      #pragma unroll
      for (int r = 0; r < 4; r++){
        float val = o[st][ni][r] / lsum[st][r];
        int s = s0w + (lg << 2) + r;
        int d = (ni << 4) + lr;
        int s2i = ((h & 3) << 8) | (b << 6) | (s >> 4);
        int c   = ((s & 15) << 6) | d;
        size_t dst = ((size_t)(h >> 2) << 20) + ((size_t)s2i << 10) + c;
        short hi = f2bf(val);
        ohi_g[dst] = hi;
        olo_g[dst] = f2bf(val - bf2f(hi));
      }
    }
  }
}

// ---------------------------------------------------------------------------
// LayerNorm over (S,E) = 1M elems per batch, three-stage.
// ---------------------------------------------------------------------------
__launch_bounds__(256)
__global__ void ln_partial_k(const float* s1, const float* s2, float2* part){
  const int tid = threadIdx.x, L = tid & 63, w = tid >> 6;
  const int b = blockIdx.y, j = blockIdx.x;
  const size_t base = ((size_t)b << 20) + ((size_t)j << 13) + ((size_t)tid << 2);
  float sum = 0.0f, ss = 0.0f;
  #pragma unroll
  for (int i = 0; i < 8; i++){
    size_t idx = base + ((size_t)i << 10);
    float4 v = *(const float4*)(s1 + idx);
    if (s2){
      float4 u = *(const float4*)(s2 + idx);
      v.x += u.x; v.y += u.y; v.z += u.z; v.w += u.w;
    }
    sum += v.x + v.y + v.z + v.w;
    ss  += v.x*v.x + v.y*v.y + v.z*v.z + v.w*v.w;
  }
  #pragma unroll
  for (int off = 1; off < 64; off <<= 1){
    sum += __shfl_xor(sum, off, 64);
    ss  += __shfl_xor(ss,  off, 64);
  }
  __shared__ float red[4][2];
  if (L == 0){ red[w][0] = sum; red[w][1] = ss; }
  __syncthreads();
  if (tid == 0){
    float s_ = red[0][0] + red[1][0] + red[2][0] + red[3][0];
    float q_ = red[0][1] + red[1][1] + red[2][1] + red[3][1];
    part[b * 128 + j] = make_float2(s_, q_);
  }
}

__launch_bounds__(64)
__global__ void ln_final_k(const float2* part, float2* stats){
  const int b = blockIdx.x, t = threadIdx.x;
  float2 a = part[b * 128 + t], c = part[b * 128 + 64 + t];
  float sum = a.x + c.x, ss = a.y + c.y;
  #pragma unroll
  for (int off = 1; off < 64; off <<= 1){
    sum += __shfl_xor(sum, off, 64);
    ss  += __shfl_xor(ss,  off, 64);
  }
  if (t == 0){
    float mean = sum * (1.0f / 1048576.0f);
    float var  = ss  * (1.0f / 1048576.0f) - mean * mean;
    stats[b] = make_float2(mean, rsqrtf(var + 1e-5f));
  }
}

// MODE 0: hi/lo planes | MODE 1: fp32 + hi/lo planes | MODE 2: fp32 out only
template<int MODE>
__launch_bounds__(256)
__global__ void ln_apply_k(const float* s1, const float* s2,
                           const float* wgt, const float* bias,
                           const float2* stats,
                           float* dstf, short* dsta, short* dstb){
  const int tid = threadIdx.x;
  const size_t base = ((size_t)blockIdx.x << 11) + ((size_t)tid << 2);
  #pragma unroll
  for (int i = 0; i < 2; i++){
    size_t idx = base + ((size_t)i << 10);
    int b = (int)(idx >> 20);
    float2 st = stats[b];
    float4 x = *(const float4*)(s1 + idx);
    if (s2){
      float4 u = *(const float4*)(s2 + idx);
      x.x += u.x; x.y += u.y; x.z += u.z; x.w += u.w;
    }
    unsigned wi = (unsigned)(idx & 1048575u);
    float4 wv = *(const float4*)(wgt + wi);
    float4 bv = *(const float4*)(bias + wi);
    float xv[4] = {x.x, x.y, x.z, x.w};
    float wvv[4] = {wv.x, wv.y, wv.z, wv.w};
    float bvv[4] = {bv.x, bv.y, bv.z, bv.w};
    float yv[4];
    #pragma unroll
    for (int c = 0; c < 4; c++)
      yv[c] = (xv[c] - st.x) * st.y * wvv[c] + bvv[c];
    if (MODE == 0 || MODE == 1){
      short h[4], l[4];
      #pragma unroll
      for (int c = 0; c < 4; c++){
        h[c] = f2bf(yv[c]);
        l[c] = f2bf(yv[c] - bf2f(h[c]));
      }
      *(short4*)(dsta + idx) = make_short4(h[0], h[1], h[2], h[3]);
      *(short4*)(dstb + idx) = make_short4(l[0], l[1], l[2], l[3]);
      if (MODE == 1)
        *(float4*)(dstf + idx) = make_float4(yv[0], yv[1], yv[2], yv[3]);
    } else {
      *(float4*)(dstf + idx) = make_float4(yv[0], yv[1], yv[2], yv[3]);
    }
  }
}

// ---------------------------------------------------------------------------
extern "C" void kernel_launch(void* const* d_in, const int* in_sizes, int n_in,
                              void* d_out, int out_size, void* d_ws, size_t ws_size,
                              hipStream_t stream){
  const float* IRf = (const float*)d_in[0];
  const float* OEf = (const float*)d_in[1];
  const float* Wq1f = (const float*)d_in[2];
  const float* Wk1f = (const float*)d_in[3];
  const float* Wv1f = (const float*)d_in[4];
  const float* Wo1f = (const float*)d_in[5];
  const float* Wq2f = (const float*)d_in[6];
  const float* Wk2f = (const float*)d_in[7];
  const float* Wv2f = (const float*)d_in[8];
  const float* Wo2f = (const float*)d_in[9];
  const float* ln1w = (const float*)d_in[10];
  const float* ln1b = (const float*)d_in[11];
  const float* ln2w = (const float*)d_in[12];
  const float* ln2b = (const float*)d_in[13];
  const float* ln3w = (const float*)d_in[14];
  const float* ln3b = (const float*)d_in[15];
  const float* W1f = (const float*)d_in[16];
  const float* b1f = (const float*)d_in[17];
  const float* W2f = (const float*)d_in[18];
  const float* b2f = (const float*)d_in[19];
  float* dout = (float*)d_out;

  char* ws = (char*)d_ws;
  const size_t MB = (size_t)1 << 20;
  short* OEh = (short*)(ws + 0*MB),  *OEl = (short*)(ws + 8*MB);
  short* IRh = (short*)(ws + 16*MB), *IRl = (short*)(ws + 24*MB);
  short* QKV1t_h = (short*)(ws + 32*MB), *QKV1t_l = (short*)(ws + 38*MB);  // [3072][1024]
  short* Wo1t_h  = (short*)(ws + 44*MB), *Wo1t_l  = (short*)(ws + 46*MB);  // [1024][1024]
  short* Q2t_h   = (short*)(ws + 48*MB), *Q2t_l   = (short*)(ws + 50*MB);
  short* KV2t_h  = (short*)(ws + 52*MB), *KV2t_l  = (short*)(ws + 56*MB);  // [2048][1024]
  short* Wo2t_h  = (short*)(ws + 60*MB), *Wo2t_l  = (short*)(ws + 62*MB);
  short* W1t_h   = (short*)(ws + 64*MB), *W1t_l   = (short*)(ws + 68*MB);  // [2048][1024]
  short* W2t_h   = (short*)(ws + 72*MB), *W2t_l   = (short*)(ws + 76*MB);  // [1024][2048]
  unsigned* q_pk = (unsigned*)(ws + 80*MB);    // packed hi|lo, 16 MB each
  unsigned* k_pk = (unsigned*)(ws + 96*MB);
  unsigned* v_pk = (unsigned*)(ws + 112*MB);
  short* outr_h = (short*)(ws + 128*MB), *outr_l = (short*)(ws + 136*MB);
  float* resid = (float*)(ws + 144*MB);
  short* attn_h = (short*)(ws + 160*MB), *attn_l = (short*)(ws + 168*MB);
  float* att2n_f = (float*)(ws + 176*MB);
  // aliases (dead ranges)
  short* hid_h = (short*)(ws + 80*MB);   // [4096][2048] over q_pk
  short* hid_l = (short*)(ws + 96*MB);   // over k_pk
  float* fc    = (float*)(ws + 112*MB);  // over v_pk
  short* a2n_h = (short*)(ws + 160*MB);  // over attn planes
  short* a2n_l = (short*)(ws + 168*MB);
  float2* part  = (float2*)(ws + 192*MB);
  float2* stats = (float2*)(ws + 192*MB + 65536);

  dim3 blk(256), blkg(512);

  // ---- split OE/IR into bf16 hi/lo planes
  SplitP sp;
  sp.src[0] = OEf; sp.hi[0] = OEh; sp.lo[0] = OEl;
  sp.src[1] = IRf; sp.hi[1] = IRh; sp.lo[1] = IRl;
  splitall_k<<<dim3(4096, 2), blk, 0, stream>>>(sp);

  // ---- batched weight transpose to [N][K] hi/lo planes
  TransP tp;
  const float* tsrc[10] = {Wq1f, Wk1f, Wv1f, Wo1f, Wq2f, Wk2f, Wv2f, Wo2f, W1f, W2f};
  short* toh[10] = {QKV1t_h, QKV1t_h + (1<<20), QKV1t_h + (2<<20), Wo1t_h,
                    Q2t_h, KV2t_h, KV2t_h + (1<<20), Wo2t_h, W1t_h, W2t_h};
  short* tol[10] = {QKV1t_l, QKV1t_l + (1<<20), QKV1t_l + (2<<20), Wo1t_l,
                    Q2t_l, KV2t_l, KV2t_l + (1<<20), Wo2t_l, W1t_l, W2t_l};
  int tK[10]   = {1024,1024,1024,1024,1024,1024,1024,1024,1024,2048};
  int tN[10]   = {1024,1024,1024,1024,1024,1024,1024,1024,2048,1024};
  int tq[10]   = {1,1,1,0,1,1,1,0,0,0};
  int tt[10]   = {256,256,256,256,256,256,256,256,512,512};
  for (int i = 0; i < 10; i++){
    tp.src[i] = tsrc[i]; tp.oh[i] = toh[i]; tp.ol[i] = tol[i];
    tp.Kd[i] = tK[i]; tp.Nd[i] = tN[i]; tp.qkv[i] = tq[i]; tp.ntiles[i] = tt[i];
  }
  transall_k<<<dim3(512, 10), blk, 0, stream>>>(tp);

  GemmP p{};

  // ===== MHA1 (self, causal) =====
  p = {OEh, OEl, 1024, QKV1t_h, QKV1t_l, 1024, 1024, 3072, nullptr, nullptr,
       nullptr, nullptr, nullptr, q_pk, k_pk, v_pk};
  gemm_k<256,6,3><<<dim3(24, 16), blkg, 0, stream>>>(p);
  flash_k<1><<<dim3(8, 64), blk, 0, stream>>>(q_pk, k_pk, v_pk, outr_h, outr_l);
  p = {outr_h, outr_l, 1024, Wo1t_h, Wo1t_l, 1024, 1024, 1024, OEf, nullptr,
       resid, nullptr, nullptr, nullptr, nullptr, nullptr};
  gemm_k<128,2,3><<<dim3(8, 32), blkg, 0, stream>>>(p);
  ln_partial_k<<<dim3(128, 4), blk, 0, stream>>>(resid, nullptr, part);
  ln_final_k<<<dim3(4), dim3(64), 0, stream>>>(part, stats);
  ln_apply_k<0><<<dim3(2048), blk, 0, stream>>>(resid, nullptr, ln1w, ln1b, stats, nullptr, attn_h, attn_l);

  // ===== MHA2 (cross: KV from inputRes, Q from att_norm, no mask) =====
  p = {attn_h, attn_l, 1024, Q2t_h, Q2t_l, 1024, 1024, 1024, nullptr, nullptr,
       nullptr, nullptr, nullptr, q_pk, nullptr, nullptr};
  gemm_k<128,0,3><<<dim3(8, 32), blkg, 0, stream>>>(p);
  p = {IRh, IRl, 1024, KV2t_h, KV2t_l, 1024, 1024, 2048, nullptr, nullptr,
       nullptr, nullptr, nullptr, k_pk, v_pk, nullptr};
  gemm_k<256,7,3><<<dim3(16, 16), blkg, 0, stream>>>(p);
  flash_k<0><<<dim3(8, 64), blk, 0, stream>>>(q_pk, k_pk, v_pk, outr_h, outr_l);
  p = {outr_h, outr_l, 1024, Wo2t_h, Wo2t_l, 1024, 1024, 1024, OEf, nullptr,
       resid, nullptr, nullptr, nullptr, nullptr, nullptr};
  gemm_k<128,2,3><<<dim3(8, 32), blkg, 0, stream>>>(p);
  ln_partial_k<<<dim3(128, 4), blk, 0, stream>>>(resid, nullptr, part);
  ln_final_k<<<dim3(4), dim3(64), 0, stream>>>(part, stats);
  ln_apply_k<1><<<dim3(2048), blk, 0, stream>>>(resid, nullptr, ln2w, ln2b, stats, att2n_f, a2n_h, a2n_l);

  // ===== FFN ((B,S,E)->(B,E,S) raw reshape is a flat no-op); 2-term =====
  p = {a2n_h, a2n_l, 1024, W1t_h, W1t_l, 1024, 1024, 2048, nullptr, b1f,
       nullptr, hid_h, hid_l, nullptr, nullptr, nullptr};
  gemm_k<256,3,2><<<dim3(16, 16), blkg, 0, stream>>>(p);
  p = {hid_h, hid_l, 2048, W2t_h, W2t_l, 2048, 2048, 1024, nullptr, b2f,
       fc, nullptr, nullptr, nullptr, nullptr, nullptr};
  gemm_k<128,4,2><<<dim3(8, 32), blkg, 0, stream>>>(p);
  ln_partial_k<<<dim3(128, 4), blk, 0, stream>>>(fc, att2n_f, part);
  ln_final_k<<<dim3(4), dim3(64), 0, stream>>>(part, stats);
  ln_apply_k<2><<<dim3(2048), blk, 0, stream>>>(fc, att2n_f, ln3w, ln3b, stats, dout, nullptr, nullptr);
}